// Round 1
// baseline (142.014 us; speedup 1.0000x reference)
//
#include <hip/hip_runtime.h>
#include <math.h>

// Problem constants: BS=8, M=64, D_IN=64, D_OUT=32; 512 tokens.
#define NLOG 20          // Chebyshev terms for log on [LOG_A, LOG_B]
#define NEXP 14          // Chebyshev terms for exp on [EXP_A, EXP_B]
#define LOG_A 0.9
#define LOG_B 7.0
#define EXP_A (-0.3)
#define EXP_B 2.1

// ws float layout
#define WS_COEF 0                      // [0..31] log coefs, [32..63] exp coefs
#define WS_NORM 64                     // nQ[512], nK[512]
#define WS_L    1088                   // per token: 3 matrices (Q,K,V logs) x 1024 f32
#define WS_WGT  (WS_L + 512*3*1024)    // weights [8][64 j][64 i]

#define FMA8A(acc, s, v0, v1) do { \
  acc[0]=fmaf((s),(v0).x,acc[0]); acc[1]=fmaf((s),(v0).y,acc[1]); \
  acc[2]=fmaf((s),(v0).z,acc[2]); acc[3]=fmaf((s),(v0).w,acc[3]); \
  acc[4]=fmaf((s),(v1).x,acc[4]); acc[5]=fmaf((s),(v1).y,acc[5]); \
  acc[6]=fmaf((s),(v1).z,acc[6]); acc[7]=fmaf((s),(v1).w,acc[7]); } while(0)

// ---------------- kernel 0: Chebyshev coefficients (double, on-device) ----------
__global__ __launch_bounds__(64) void k_coef(float* __restrict__ cws) {
  int j = threadIdx.x;
  const double PI = 3.14159265358979323846;
  if (j < NLOG) {
    double mid = 0.5*(LOG_A+LOG_B), hf = 0.5*(LOG_B-LOG_A);
    double s = 0.0;
    for (int k = 0; k < NLOG; ++k) {
      double th = PI*(k+0.5)/NLOG;
      s += log(mid + hf*cos(th)) * cos(j*th);
    }
    cws[j] = (float)(2.0*s/NLOG);
  }
  if (j < NEXP) {
    double mid = 0.5*(EXP_A+EXP_B), hf = 0.5*(EXP_B-EXP_A);
    double s = 0.0;
    for (int k = 0; k < NEXP; ++k) {
      double th = PI*(k+0.5)/NEXP;
      s += exp(mid + hf*cos(th)) * cos(j*th);
    }
    cws[32 + j] = (float)(2.0*s/NEXP);
  }
}

// ---------------- wave-level Clenshaw: res = p(Y), Y symmetric 32x32 in LDS -----
// One wave (64 lanes). Lane owns rows {rg, rg+16}, cols j0..j0+7 (rg=l>>2, cg=l&3).
// Y rows held in registers; B iterates through two LDS buffers (stride 36).
__device__ __forceinline__ void wave_matpoly(
    const float* __restrict__ coef, int nterms,
    const float* sY, float* b0, float* b1,
    int rg, int cg, float resA[8], float resB[8])
{
  float yA[32], yB[32];
#pragma unroll
  for (int q = 0; q < 8; ++q) {
    float4 a = *(const float4*)(sY + rg*36 + 4*q);
    float4 b = *(const float4*)(sY + (rg+16)*36 + 4*q);
    yA[4*q+0]=a.x; yA[4*q+1]=a.y; yA[4*q+2]=a.z; yA[4*q+3]=a.w;
    yB[4*q+0]=b.x; yB[4*q+1]=b.y; yB[4*q+2]=b.z; yB[4*q+3]=b.w;
  }
  const int j0 = 8*cg;
  float cn = coef[nterms-1];
#pragma unroll
  for (int h = 0; h < 2; ++h) {
    int row = rg + 16*h;
    float v[8];
#pragma unroll
    for (int c = 0; c < 8; ++c) v[c] = (j0 + c == row) ? cn : 0.0f;
    *(float4*)(b1 + row*36 + j0)   = make_float4(v[0],v[1],v[2],v[3]);
    *(float4*)(b1 + row*36 + j0+4) = make_float4(v[4],v[5],v[6],v[7]);
    *(float4*)(b0 + row*36 + j0)   = make_float4(0.f,0.f,0.f,0.f);
    *(float4*)(b0 + row*36 + j0+4) = make_float4(0.f,0.f,0.f,0.f);
  }
  __syncthreads();
  float* bc = b1;   // holds b_{k+1}
  float* bp = b0;   // holds b_{k+2}
#pragma unroll 1
  for (int kk = nterms-2; kk >= 0; --kk) {
    float a0[8], a1[8];
#pragma unroll
    for (int c = 0; c < 8; ++c) { a0[c]=0.f; a1[c]=0.f; }
#pragma unroll
    for (int k = 0; k < 32; ++k) {
      float4 v0 = *(const float4*)(bc + k*36 + j0);
      float4 v1 = *(const float4*)(bc + k*36 + j0 + 4);
      FMA8A(a0, yA[k], v0, v1);
      FMA8A(a1, yB[k], v0, v1);
    }
    if (kk >= 1) {
      float ck = coef[kk];
#pragma unroll
      for (int h = 0; h < 2; ++h) {
        int row = rg + 16*h;
        float* ac = h ? a1 : a0;
        float4 p0 = *(const float4*)(bp + row*36 + j0);
        float4 p1 = *(const float4*)(bp + row*36 + j0 + 4);
        float n[8];
        n[0]=2.f*ac[0]-p0.x; n[1]=2.f*ac[1]-p0.y; n[2]=2.f*ac[2]-p0.z; n[3]=2.f*ac[3]-p0.w;
        n[4]=2.f*ac[4]-p1.x; n[5]=2.f*ac[5]-p1.y; n[6]=2.f*ac[6]-p1.z; n[7]=2.f*ac[7]-p1.w;
#pragma unroll
        for (int c = 0; c < 8; ++c) if (j0 + c == row) n[c] += ck;
        *(float4*)(bp + row*36 + j0)   = make_float4(n[0],n[1],n[2],n[3]);
        *(float4*)(bp + row*36 + j0+4) = make_float4(n[4],n[5],n[6],n[7]);
      }
      __syncthreads();
      float* tm = bc; bc = bp; bp = tm;
    } else {
      // final: f = Y*b1 - b2 + (c0/2) I
      float c0h = 0.5f*coef[0];
#pragma unroll
      for (int h = 0; h < 2; ++h) {
        int row = rg + 16*h;
        float* ac = h ? a1 : a0;
        float* rs = h ? resB : resA;
        float4 p0 = *(const float4*)(bp + row*36 + j0);
        float4 p1 = *(const float4*)(bp + row*36 + j0 + 4);
        rs[0]=ac[0]-p0.x; rs[1]=ac[1]-p0.y; rs[2]=ac[2]-p0.z; rs[3]=ac[3]-p0.w;
        rs[4]=ac[4]-p1.x; rs[5]=ac[5]-p1.y; rs[6]=ac[6]-p1.z; rs[7]=ac[7]-p1.w;
#pragma unroll
        for (int c = 0; c < 8; ++c) if (j0 + c == row) rs[c] += c0h;
      }
    }
  }
}

// ---------------- kernel 1: S = W X W^T, then log(S) via Clenshaw ---------------
// grid 1536 = 512 tokens x {Q,K,V}; 64 threads (1 wave).
__global__ __launch_bounds__(64) void k_logqkv(
    const float* __restrict__ X, const float* __restrict__ Wq,
    const float* __restrict__ Wk, const float* __restrict__ Wv,
    const float* __restrict__ cws, float* __restrict__ L, float* __restrict__ norms)
{
  __shared__ float pool[8544];
  float* sX  = pool;          // [64][65] (phase 1)
  float* sW  = pool + 4160;   // [32][65]
  float* sU  = pool + 6240;   // [64][36]
  float* sY  = pool;          // [32][36] overlays sX (phase 2)
  float* sB0 = pool + 1152;   // overlays sX
  float* sB1 = pool + 2304;   // overlays sX

  int gid = blockIdx.x;
  int token = gid / 3, which = gid - token*3;
  const float* W = (which == 0) ? Wq : ((which == 1) ? Wk : Wv);
  int l = threadIdx.x;
  int rg = l >> 2, cg = l & 3;
  int j0 = 8*cg;

  const float* Xg = X + (size_t)token*4096;
#pragma unroll
  for (int q = 0; q < 16; ++q) {
    int idx = q*256 + l*4;
    float4 v = *(const float4*)(Xg + idx);
    int r = idx >> 6, c = idx & 63;
    float* d = sX + r*65 + c;
    d[0]=v.x; d[1]=v.y; d[2]=v.z; d[3]=v.w;
  }
#pragma unroll
  for (int q = 0; q < 8; ++q) {
    int idx = q*256 + l*4;
    float4 v = *(const float4*)(W + idx);
    int r = idx >> 6, c = idx & 63;
    float* d = sW + r*65 + c;
    d[0]=v.x; d[1]=v.y; d[2]=v.z; d[3]=v.w;
  }
  __syncthreads();

  // U = X * W^T (64x32): lane rows rg+16s (s=0..3), cols j0..j0+7
  float u[4][8];
#pragma unroll
  for (int s = 0; s < 4; ++s)
#pragma unroll
    for (int c = 0; c < 8; ++c) u[s][c] = 0.f;
#pragma unroll 4
  for (int j = 0; j < 64; ++j) {
    float xs[4];
#pragma unroll
    for (int s = 0; s < 4; ++s) xs[s] = sX[(rg+16*s)*65 + j];
    float wv[8];
#pragma unroll
    for (int c = 0; c < 8; ++c) wv[c] = sW[(j0+c)*65 + j];
#pragma unroll
    for (int s = 0; s < 4; ++s)
#pragma unroll
      for (int c = 0; c < 8; ++c) u[s][c] = fmaf(xs[s], wv[c], u[s][c]);
  }
#pragma unroll
  for (int s = 0; s < 4; ++s) {
    int row = rg + 16*s;
    *(float4*)(sU + row*36 + j0)   = make_float4(u[s][0],u[s][1],u[s][2],u[s][3]);
    *(float4*)(sU + row*36 + j0+4) = make_float4(u[s][4],u[s][5],u[s][6],u[s][7]);
  }
  __syncthreads();   // after this no lane reads sX again -> sY overlay safe

  // S = W * U (32x32): lane rows {rg, rg+16}, cols j0..j0+7; scale into sY
  float s0[8], s1[8];
#pragma unroll
  for (int c = 0; c < 8; ++c) { s0[c]=0.f; s1[c]=0.f; }
#pragma unroll 4
  for (int i = 0; i < 64; ++i) {
    float w0 = sW[rg*65 + i], w1 = sW[(rg+16)*65 + i];
    float4 uv0 = *(const float4*)(sU + i*36 + j0);
    float4 uv1 = *(const float4*)(sU + i*36 + j0 + 4);
    FMA8A(s0, w0, uv0, uv1);
    FMA8A(s1, w1, uv0, uv1);
  }
  const float scl = (float)(2.0/(LOG_B-LOG_A));
  const float shf = (float)((LOG_A+LOG_B)/(LOG_B-LOG_A));
#pragma unroll
  for (int h = 0; h < 2; ++h) {
    int row = rg + 16*h;
    float* sv = h ? s1 : s0;
    float v[8];
#pragma unroll
    for (int c = 0; c < 8; ++c) v[c] = scl*sv[c] - ((j0+c==row) ? shf : 0.f);
    *(float4*)(sY + row*36 + j0)   = make_float4(v[0],v[1],v[2],v[3]);
    *(float4*)(sY + row*36 + j0+4) = make_float4(v[4],v[5],v[6],v[7]);
  }
  __syncthreads();

  float resA[8], resB[8];
  wave_matpoly(cws, NLOG, sY, sB0, sB1, rg, cg, resA, resB);

  float* Lg = L + ((size_t)token*3 + which)*1024;
  *(float4*)(Lg + rg*32 + j0)        = make_float4(resA[0],resA[1],resA[2],resA[3]);
  *(float4*)(Lg + rg*32 + j0 + 4)    = make_float4(resA[4],resA[5],resA[6],resA[7]);
  *(float4*)(Lg + (rg+16)*32 + j0)   = make_float4(resB[0],resB[1],resB[2],resB[3]);
  *(float4*)(Lg + (rg+16)*32 + j0+4) = make_float4(resB[4],resB[5],resB[6],resB[7]);

  if (which < 2) {
    float nrm = 0.f;
#pragma unroll
    for (int c = 0; c < 8; ++c) nrm += resA[c]*resA[c] + resB[c]*resB[c];
#pragma unroll
    for (int off = 32; off >= 1; off >>= 1) nrm += __shfl_xor(nrm, off);
    if (l == 0) norms[which*512 + token] = nrm;
  }
}

// ---------------- kernel 2: energies + softmax over i -> weights ----------------
// grid 32 = 8 b x 4 jseg(16); 256 threads.
__global__ __launch_bounds__(256) void k_energy(
    const float* __restrict__ L, const float* __restrict__ norms,
    float* __restrict__ wgt)
{
  __shared__ float sLK[64*68];
  __shared__ float sLQ[16*68];
  __shared__ float sE[64*17];
  __shared__ float sMax[16];
  __shared__ float sInv[16];
  int b   = blockIdx.x >> 2;
  int j0s = (blockIdx.x & 3) * 16;
  int t = threadIdx.x;
  int ti = t >> 3, tj = t & 7;
  float acc00=0.f, acc01=0.f, acc10=0.f, acc11=0.f;
  for (int kb = 0; kb < 16; ++kb) {
    __syncthreads();
#pragma unroll
    for (int q = 0; q < 4; ++q) {
      int flat = 4*(t + 256*q);
      int i = flat >> 6, c = flat & 63;
      float4 v = *(const float4*)(L + (((size_t)(b*64 + i))*3 + 1)*1024 + kb*64 + c);
      *(float4*)(sLK + i*68 + c) = v;
    }
    {
      int flat = 4*t;
      int jj = flat >> 6, c = flat & 63;
      float4 v = *(const float4*)(L + (((size_t)(b*64 + j0s + jj))*3 + 0)*1024 + kb*64 + c);
      *(float4*)(sLQ + jj*68 + c) = v;
    }
    __syncthreads();
#pragma unroll
    for (int kq = 0; kq < 16; ++kq) {
      int k = 4*kq;
      float4 ka = *(const float4*)(sLK + ti*68 + k);
      float4 kb4= *(const float4*)(sLK + (ti+32)*68 + k);
      float4 qa = *(const float4*)(sLQ + tj*68 + k);
      float4 qb = *(const float4*)(sLQ + (tj+8)*68 + k);
      acc00 = fmaf(ka.x,qa.x, fmaf(ka.y,qa.y, fmaf(ka.z,qa.z, fmaf(ka.w,qa.w, acc00))));
      acc01 = fmaf(ka.x,qb.x, fmaf(ka.y,qb.y, fmaf(ka.z,qb.z, fmaf(ka.w,qb.w, acc01))));
      acc10 = fmaf(kb4.x,qa.x, fmaf(kb4.y,qa.y, fmaf(kb4.z,qa.z, fmaf(kb4.w,qa.w, acc10))));
      acc11 = fmaf(kb4.x,qb.x, fmaf(kb4.y,qb.y, fmaf(kb4.z,qb.z, fmaf(kb4.w,qb.w, acc11))));
    }
  }
  float nk0 = norms[512 + b*64 + ti];
  float nk1 = norms[512 + b*64 + ti + 32];
  float nq0 = norms[b*64 + j0s + tj];
  float nq1 = norms[b*64 + j0s + tj + 8];
  sE[ti*17 + tj]          = 1.f/(1.f + log1pf(fmaxf(nq0 + nk0 - 2.f*acc00, 0.f)));
  sE[ti*17 + tj + 8]      = 1.f/(1.f + log1pf(fmaxf(nq1 + nk0 - 2.f*acc01, 0.f)));
  sE[(ti+32)*17 + tj]     = 1.f/(1.f + log1pf(fmaxf(nq0 + nk1 - 2.f*acc10, 0.f)));
  sE[(ti+32)*17 + tj + 8] = 1.f/(1.f + log1pf(fmaxf(nq1 + nk1 - 2.f*acc11, 0.f)));
  __syncthreads();
  if (t < 16) {
    float m = -1e30f;
    for (int i = 0; i < 64; ++i) m = fmaxf(m, sE[i*17 + t]);
    float s = 0.f;
    for (int i = 0; i < 64; ++i) s += expf(sE[i*17 + t] - m);
    sMax[t] = m; sInv[t] = 1.f/s;
  }
  __syncthreads();
#pragma unroll
  for (int q = 0; q < 4; ++q) {
    int f = t + 256*q;
    int jl = f >> 6, i = f & 63;
    float w = expf(sE[i*17 + jl] - sMax[jl]) * sInv[jl];
    wgt[((size_t)(b*64 + j0s + jl))*64 + i] = w;
  }
}

// ---------------- kernel 3: mean_log (weighted) + matrix exp --------------------
// grid 512 = (b,j); 64 threads (1 wave).
__global__ __launch_bounds__(64) void k_meanexp(
    const float* __restrict__ L, const float* __restrict__ wgt,
    const float* __restrict__ cws, float* __restrict__ out)
{
  __shared__ float sWr[64];
  __shared__ float sY[1152];
  __shared__ float sB0[1152];
  __shared__ float sB1[1152];
  int bj = blockIdx.x;
  int b = bj >> 6;
  int l = threadIdx.x;
  int rg = l >> 2, cg = l & 3, j0 = 8*cg;
  sWr[l] = wgt[(size_t)bj*64 + l];
  __syncthreads();
  float m0[8], m1[8];
#pragma unroll
  for (int c = 0; c < 8; ++c) { m0[c]=0.f; m1[c]=0.f; }
#pragma unroll 4
  for (int i = 0; i < 64; ++i) {
    float wv = sWr[i];
    const float* lv = L + (((size_t)(b*64 + i))*3 + 2)*1024;
    float4 v00 = *(const float4*)(lv + rg*32 + j0);
    float4 v01 = *(const float4*)(lv + rg*32 + j0 + 4);
    float4 v10 = *(const float4*)(lv + (rg+16)*32 + j0);
    float4 v11 = *(const float4*)(lv + (rg+16)*32 + j0 + 4);
    FMA8A(m0, wv, v00, v01);
    FMA8A(m1, wv, v10, v11);
  }
  const float scl = (float)(2.0/(EXP_B-EXP_A));
  const float shf = (float)((EXP_A+EXP_B)/(EXP_B-EXP_A));
#pragma unroll
  for (int h = 0; h < 2; ++h) {
    int row = rg + 16*h;
    float* mv = h ? m1 : m0;
    float v[8];
#pragma unroll
    for (int c = 0; c < 8; ++c) v[c] = scl*mv[c] - ((j0+c==row) ? shf : 0.f);
    *(float4*)(sY + row*36 + j0)   = make_float4(v[0],v[1],v[2],v[3]);
    *(float4*)(sY + row*36 + j0+4) = make_float4(v[4],v[5],v[6],v[7]);
  }
  __syncthreads();
  float resA[8], resB[8];
  wave_matpoly(cws + 32, NEXP, sY, sB0, sB1, rg, cg, resA, resB);
  float* og = out + (size_t)bj*1024;
  *(float4*)(og + rg*32 + j0)        = make_float4(resA[0],resA[1],resA[2],resA[3]);
  *(float4*)(og + rg*32 + j0 + 4)    = make_float4(resA[4],resA[5],resA[6],resA[7]);
  *(float4*)(og + (rg+16)*32 + j0)   = make_float4(resB[0],resB[1],resB[2],resB[3]);
  *(float4*)(og + (rg+16)*32 + j0+4) = make_float4(resB[4],resB[5],resB[6],resB[7]);
}

extern "C" void kernel_launch(void* const* d_in, const int* in_sizes, int n_in,
                              void* d_out, int out_size, void* d_ws, size_t ws_size,
                              hipStream_t stream) {
  const float* X  = (const float*)d_in[0];
  const float* Wq = (const float*)d_in[1];
  const float* Wk = (const float*)d_in[2];
  const float* Wv = (const float*)d_in[3];
  float* out = (float*)d_out;
  float* ws  = (float*)d_ws;
  float* cws   = ws + WS_COEF;
  float* norms = ws + WS_NORM;
  float* L     = ws + WS_L;
  float* wgt   = ws + WS_WGT;

  hipLaunchKernelGGL(k_coef,    dim3(1),    dim3(64),  0, stream, cws);
  hipLaunchKernelGGL(k_logqkv,  dim3(1536), dim3(64),  0, stream, X, Wq, Wk, Wv, cws, L, norms);
  hipLaunchKernelGGL(k_energy,  dim3(32),   dim3(256), 0, stream, L, norms, wgt);
  hipLaunchKernelGGL(k_meanexp, dim3(512),  dim3(64),  0, stream, L, wgt, cws, out);
}

// Round 2
// 74.868 us; speedup vs baseline: 1.8969x; 1.8969x over previous
//
#include <hip/hip_runtime.h>
#include <math.h>

// BS=8, M=64, D_IN=64, D_OUT=32; 512 tokens, 1536 (token,which) matrices.
#define NLOG 20
#define NEXP 14
#define LOG_A 0.9
#define LOG_B 7.0
#define EXP_A (-0.3)
#define EXP_B 2.1

// ws element-offset layout (all 16B-aligned)
#define WS_COEF 0            // 64 f32
#define WS_NORM 64           // 1024 f32 (nQ[512], nK[512])
#define WS_WGT  1088         // 32768 f32 [bj][i]
#define WS_LV   33856        // 524288 f32: V-logs lane-major [token][lane*16+reg]
#define WS_QHI  558144       // 262144 u32 per plane
#define WS_QLO  820288
#define WS_KHI  1082432
#define WS_KLO  1344576      // ends 1606720 f32 = 6.43 MB

typedef float  f32x16 __attribute__((ext_vector_type(16)));
typedef short  short8 __attribute__((ext_vector_type(8)));
typedef unsigned int u32;

union F8 { short8 s; u32 u[4]; uint4 v; };

__device__ __forceinline__ u32 pkbf16(float a, float b) {
  u32 r;
  asm("v_cvt_pk_bf16_f32 %0, %1, %2" : "=v"(r) : "v"(a), "v"(b));
  return r;
}
__device__ __forceinline__ u32 xor32(u32 x) {
  return (u32)__shfl_xor((int)x, 32, 64);
}
__device__ __forceinline__ f32x16 MFMA(short8 a, short8 b, f32x16 c) {
  return __builtin_amdgcn_mfma_f32_32x32x16_bf16(a, b, c, 0, 0, 0);
}
#define Z16 {0.f,0.f,0.f,0.f,0.f,0.f,0.f,0.f,0.f,0.f,0.f,0.f,0.f,0.f,0.f,0.f}

// split 8 f32 into hi/lo bf16 fragments (pair-packed, element e -> k offset e)
__device__ __forceinline__ void pack8(const float* d, F8& hi, F8& lo) {
#pragma unroll
  for (int j = 0; j < 4; ++j) {
    float a = d[2*j], b = d[2*j+1];
    u32 hw = pkbf16(a, b);
    hi.u[j] = hw;
    float ha = __uint_as_float(hw << 16);
    float hb = __uint_as_float(hw & 0xffff0000u);
    lo.u[j] = pkbf16(a - ha, b - hb);
  }
}
__device__ __forceinline__ void packpairs(const float* d, u32* wh, u32* wl) {
  F8 a, b;
  pack8(d, a, b);
#pragma unroll
  for (int j = 0; j < 4; ++j) { wh[j] = a.u[j]; wl[j] = b.u[j]; }
  pack8(d + 8, a, b);
#pragma unroll
  for (int j = 0; j < 4; ++j) { wh[4+j] = a.u[j]; wl[4+j] = b.u[j]; }
}

// D-layout f32[16] (col=lane&31, row=(reg&3)+8*(reg>>2)+4*(lane>>5)) ->
// 4 frags: fr[0]=k0..15 hi, fr[1]=k0..15 lo, fr[2]=k16..31 hi, fr[3]=k16..31 lo.
// Frag slot (lane,e): value M[k = 8*(lane>>5)+e (+16*chunk)][col = lane&31].
__device__ __forceinline__ void d2frags(const float* d, int lo_half, F8 fr[4]) {
  u32 wh[8], wl[8];
  packpairs(d, wh, wl);
#pragma unroll
  for (int s = 0; s < 2; ++s) {
    const u32* w = s ? wl : wh;
    u32 c0=xor32(w[0]), c1=xor32(w[1]), c2=xor32(w[2]), c3=xor32(w[3]);
    u32 c4=xor32(w[4]), c5=xor32(w[5]), c6=xor32(w[6]), c7=xor32(w[7]);
    F8& f1 = fr[s];   F8& f2 = fr[2+s];
    f1.u[0] = lo_half ? w[0] : c2;
    f1.u[1] = lo_half ? w[1] : c3;
    f1.u[2] = lo_half ? c0   : w[2];
    f1.u[3] = lo_half ? c1   : w[3];
    f2.u[0] = lo_half ? w[4] : c6;
    f2.u[1] = lo_half ? w[5] : c7;
    f2.u[2] = lo_half ? c4   : w[6];
    f2.u[3] = lo_half ? c5   : w[7];
  }
}

__device__ __forceinline__ void mk_dm(int col, int h, float* dm) {
#pragma unroll
  for (int i = 0; i < 16; ++i) {
    int ro = (i & 3) + 8*(i >> 2) + 4*h;
    dm[i] = (ro == col) ? 1.f : 0.f;
  }
}

// res = p(Y) via Clenshaw; Yf = frags of symmetric Y; all state in D-layout regs.
__device__ __forceinline__ void wave_clenshaw(
    const float* __restrict__ coef, int nterms,
    const F8 Yf[4], const float* dm, int lo_half, float* res)
{
  float bc[16], bp[16];
  float cn = coef[nterms-1];
#pragma unroll
  for (int i = 0; i < 16; ++i) { bc[i] = cn*dm[i]; bp[i] = 0.f; }
  for (int kk = nterms-2; kk >= 1; --kk) {
    F8 bf[4];
    d2frags(bc, lo_half, bf);
    f32x16 acc = Z16;
    acc = MFMA(Yf[0].s, bf[0].s, acc);
    acc = MFMA(Yf[0].s, bf[1].s, acc);
    acc = MFMA(Yf[1].s, bf[0].s, acc);
    acc = MFMA(Yf[2].s, bf[2].s, acc);
    acc = MFMA(Yf[2].s, bf[3].s, acc);
    acc = MFMA(Yf[3].s, bf[2].s, acc);
    float ck = coef[kk];
#pragma unroll
    for (int i = 0; i < 16; ++i) {
      float nb = 2.f*acc[i] - bp[i] + ck*dm[i];
      bp[i] = bc[i]; bc[i] = nb;
    }
  }
  F8 bf[4];
  d2frags(bc, lo_half, bf);
  f32x16 acc = Z16;
  acc = MFMA(Yf[0].s, bf[0].s, acc);
  acc = MFMA(Yf[0].s, bf[1].s, acc);
  acc = MFMA(Yf[1].s, bf[0].s, acc);
  acc = MFMA(Yf[2].s, bf[2].s, acc);
  acc = MFMA(Yf[2].s, bf[3].s, acc);
  acc = MFMA(Yf[3].s, bf[2].s, acc);
  float c0h = 0.5f*coef[0];
#pragma unroll
  for (int i = 0; i < 16; ++i) res[i] = acc[i] - bp[i] + c0h*dm[i];
}

// ---------------- kernel 0: Chebyshev coefficients (parallel over terms) -------
__global__ __launch_bounds__(768) void k_coef(float* __restrict__ cws) {
  __shared__ double st[400];
  __shared__ double se[196];
  int t = threadIdx.x;
  const double PI = 3.14159265358979323846;
  if (t < 400) {
    int j = t / 20, k = t % 20;
    double th = PI*(k + 0.5)/20.0;
    st[t] = log(0.5*(LOG_A+LOG_B) + 0.5*(LOG_B-LOG_A)*cos(th)) * cos(j*th);
  }
  if (t >= 512 && t < 708) {
    int q = t - 512; int j = q / 14, k = q % 14;
    double th = PI*(k + 0.5)/14.0;
    se[q] = exp(0.5*(EXP_A+EXP_B) + 0.5*(EXP_B-EXP_A)*cos(th)) * cos(j*th);
  }
  __syncthreads();
  if (t < 20) {
    double s = 0.0;
    for (int k = 0; k < 20; ++k) s += st[t*20 + k];
    cws[t] = (float)(s / 10.0);           // 2s/20
  }
  if (t >= 32 && t < 46) {
    int j = t - 32; double s = 0.0;
    for (int k = 0; k < 14; ++k) s += se[j*14 + k];
    cws[32 + j] = (float)(s / 7.0);       // 2s/14
  }
}

// ---------------- kernel 1: S = W X W^T -> log(S), all MFMA, zero LDS ----------
// grid 1536 = 512 tokens x {Q,K,V}; 64 threads (1 wave).
__global__ __launch_bounds__(64, 2) void k_logqkv(
    const float* __restrict__ X, const float* __restrict__ Wq,
    const float* __restrict__ Wk, const float* __restrict__ Wv,
    float* __restrict__ ws)
{
  const float* cws = ws + WS_COEF;
  int gid = blockIdx.x;
  int token = gid / 3, which = gid - token*3;
  const float* W = (which == 0) ? Wq : ((which == 1) ? Wk : Wv);
  int l = threadIdx.x;
  int col = l & 31, h = l >> 5;
  int lo_half = (h == 0);

  // W fragments: Wf[2c]=hi, Wf[2c+1]=lo; slot value W[col][16c+8h+e]
  F8 Wf[8];
#pragma unroll
  for (int c = 0; c < 4; ++c) {
    const float* wp = W + col*64 + 16*c + 8*h;
    float d8[8];
    float4 v0 = *(const float4*)(wp);
    float4 v1 = *(const float4*)(wp + 4);
    d8[0]=v0.x; d8[1]=v0.y; d8[2]=v0.z; d8[3]=v0.w;
    d8[4]=v1.x; d8[5]=v1.y; d8[6]=v1.z; d8[7]=v1.w;
    pack8(d8, Wf[2*c], Wf[2*c+1]);
  }

  // U = X * W^T (64x32) as two 32-row blocks
  f32x16 Ua = Z16, Ub = Z16;
#pragma unroll
  for (int rb = 0; rb < 2; ++rb) {
#pragma unroll
    for (int c = 0; c < 4; ++c) {
      const float* xp = X + (size_t)token*4096 + (size_t)(col + 32*rb)*64 + 16*c + 8*h;
      float d8[8];
      float4 v0 = *(const float4*)(xp);
      float4 v1 = *(const float4*)(xp + 4);
      d8[0]=v0.x; d8[1]=v0.y; d8[2]=v0.z; d8[3]=v0.w;
      d8[4]=v1.x; d8[5]=v1.y; d8[6]=v1.z; d8[7]=v1.w;
      F8 xh, xl;
      pack8(d8, xh, xl);
      f32x16& U = rb ? Ub : Ua;
      U = MFMA(xh.s, Wf[2*c].s,   U);
      U = MFMA(xh.s, Wf[2*c+1].s, U);
      U = MFMA(xl.s, Wf[2*c].s,   U);
    }
  }

  // U (D-layout) -> B-frags for S-step: chunks 0..3 of K=64
  float ua[16], ub[16];
#pragma unroll
  for (int i = 0; i < 16; ++i) { ua[i] = Ua[i]; ub[i] = Ub[i]; }
  F8 Uf[8], t4[4];
  d2frags(ua, lo_half, t4);
  Uf[0]=t4[0]; Uf[1]=t4[1]; Uf[2]=t4[2]; Uf[3]=t4[3];
  d2frags(ub, lo_half, t4);
  Uf[4]=t4[0]; Uf[5]=t4[1]; Uf[6]=t4[2]; Uf[7]=t4[3];

  // S = W * U (32x32)
  f32x16 S = Z16;
#pragma unroll
  for (int c = 0; c < 4; ++c) {
    S = MFMA(Wf[2*c].s,   Uf[2*c].s,   S);
    S = MFMA(Wf[2*c].s,   Uf[2*c+1].s, S);
    S = MFMA(Wf[2*c+1].s, Uf[2*c].s,   S);
  }

  // affine map to Chebyshev domain, then log via Clenshaw
  float dm[16], y[16], res[16];
  mk_dm(col, h, dm);
  const float scl = (float)(2.0/(LOG_B-LOG_A));
  const float shf = (float)((LOG_A+LOG_B)/(LOG_B-LOG_A));
#pragma unroll
  for (int i = 0; i < 16; ++i) y[i] = scl*S[i] - shf*dm[i];
  F8 Yf[4];
  d2frags(y, lo_half, Yf);
  wave_clenshaw(cws, NLOG, Yf, dm, lo_half, res);

  if (which == 2) {
    float* LV = ws + WS_LV + (size_t)token*1024 + l*16;
#pragma unroll
    for (int g = 0; g < 4; ++g)
      *(float4*)(LV + 4*g) = make_float4(res[4*g], res[4*g+1], res[4*g+2], res[4*g+3]);
  } else {
    u32 wh[8], wl[8];
    packpairs(res, wh, wl);
    u32* hp = (u32*)ws + (which ? WS_KHI : WS_QHI) + (size_t)token*512 + l*8;
    u32* lp = (u32*)ws + (which ? WS_KLO : WS_QLO) + (size_t)token*512 + l*8;
    *(uint4*)(hp)     = make_uint4(wh[0], wh[1], wh[2], wh[3]);
    *(uint4*)(hp + 4) = make_uint4(wh[4], wh[5], wh[6], wh[7]);
    *(uint4*)(lp)     = make_uint4(wl[0], wl[1], wl[2], wl[3]);
    *(uint4*)(lp + 4) = make_uint4(wl[4], wl[5], wl[6], wl[7]);
    float nrm = 0.f;
#pragma unroll
    for (int i = 0; i < 16; ++i) nrm += res[i]*res[i];
#pragma unroll
    for (int off = 32; off >= 1; off >>= 1) nrm += __shfl_xor(nrm, off, 64);
    if (l == 0) ws[WS_NORM + which*512 + token] = nrm;
  }
}

// ---------------- kernel 2: Gram via MFMA + energies + softmax -> weights ------
// grid 16 = 8 b x 2 jt(32 j each); 256 threads = 4 waves (rb = w&1, kh = w>>1).
__global__ __launch_bounds__(256) void k_energy(float* __restrict__ ws)
{
  __shared__ float sG[2][32][68];
  __shared__ float sS[32][68];
  __shared__ float sMax[32], sInv[32];
  const u32* Qhi = (const u32*)ws + WS_QHI;
  const u32* Qlo = (const u32*)ws + WS_QLO;
  const u32* Khi = (const u32*)ws + WS_KHI;
  const u32* Klo = (const u32*)ws + WS_KLO;
  const float* norms = ws + WS_NORM;
  float* wgt = ws + WS_WGT;

  int b = blockIdx.x >> 1, j0 = (blockIdx.x & 1)*32;
  int t = threadIdx.x;
  int w = t >> 6, l = t & 63;
  int rb = w & 1, kh = w >> 1;
  int col = l & 31, h = l >> 5;
  int itok = b*64 + rb*32 + col;   // A rows: K-logs
  int jtok = b*64 + j0 + col;      // B cols: Q-logs

  const u32* Ah = Khi + (size_t)itok*512;
  const u32* Al = Klo + (size_t)itok*512;
  const u32* Bh = Qhi + (size_t)jtok*512;
  const u32* Bl = Qlo + (size_t)jtok*512;

  f32x16 acc = Z16;
  for (int c = kh*32; c < kh*32 + 32; ++c) {
    int off = 8*c + 4*h;
    F8 ah, al, bh, bl;
    ah.v = *(const uint4*)(Ah + off);
    al.v = *(const uint4*)(Al + off);
    bh.v = *(const uint4*)(Bh + off);
    bl.v = *(const uint4*)(Bl + off);
    acc = MFMA(ah.s, bh.s, acc);
    acc = MFMA(ah.s, bl.s, acc);
    acc = MFMA(al.s, bh.s, acc);
  }
#pragma unroll
  for (int g = 0; g < 4; ++g) {
    int ro = rb*32 + 8*g + 4*h;
    *(float4*)(&sG[kh][col][ro]) = make_float4(acc[4*g], acc[4*g+1], acc[4*g+2], acc[4*g+3]);
  }
  __syncthreads();

  int j = t & 31, ig = t >> 5;
  float nq = norms[b*64 + j0 + j];
#pragma unroll
  for (int i = ig*8; i < ig*8 + 8; ++i) {
    float g = sG[0][j][i] + sG[1][j][i];
    float e = fmaxf(norms[512 + b*64 + i] + nq - 2.f*g, 0.f);
    sS[j][i] = 1.f/(1.f + log1pf(e));
  }
  __syncthreads();
  if (t < 32) {
    float m = -1e30f;
    for (int i = 0; i < 64; ++i) m = fmaxf(m, sS[t][i]);
    float s = 0.f;
    for (int i = 0; i < 64; ++i) s += expf(sS[t][i] - m);
    sMax[t] = m; sInv[t] = 1.f/s;
  }
  __syncthreads();
  float m = sMax[j], inv = sInv[j];
#pragma unroll
  for (int i = ig*8; i < ig*8 + 8; ++i)
    wgt[(size_t)(b*64 + j0 + j)*64 + i] = expf(sS[j][i] - m)*inv;
}

// ---------------- kernel 3: weighted log-mean + matrix exp (MFMA Clenshaw) -----
// grid 128; 256 threads = 4 waves, wave = one (b,j).
__global__ __launch_bounds__(256, 2) void k_meanexp(
    const float* __restrict__ ws_c, float* __restrict__ out)
{
  __shared__ float sW[4][64];
  const float* cws = ws_c + WS_COEF;
  const float* LV  = ws_c + WS_LV;
  const float* wgt = ws_c + WS_WGT;

  int wv = threadIdx.x >> 6, l = threadIdx.x & 63;
  int bj = blockIdx.x*4 + wv;
  int b = bj >> 6;
  int col = l & 31, h = l >> 5;
  int lo_half = (h == 0);

  sW[wv][l] = wgt[(size_t)bj*64 + l];   // intra-wave LDS: in-order, no barrier

  float acc[16];
#pragma unroll
  for (int i = 0; i < 16; ++i) acc[i] = 0.f;
  const float* vb = LV + (size_t)b*65536 + l*16;
  for (int i = 0; i < 64; ++i) {
    float wi = sW[wv][i];
    const float* vp = vb + (size_t)i*1024;
    float4 a0 = *(const float4*)(vp);
    float4 a1 = *(const float4*)(vp + 4);
    float4 a2 = *(const float4*)(vp + 8);
    float4 a3 = *(const float4*)(vp + 12);
    acc[0]  = fmaf(wi, a0.x, acc[0]);  acc[1]  = fmaf(wi, a0.y, acc[1]);
    acc[2]  = fmaf(wi, a0.z, acc[2]);  acc[3]  = fmaf(wi, a0.w, acc[3]);
    acc[4]  = fmaf(wi, a1.x, acc[4]);  acc[5]  = fmaf(wi, a1.y, acc[5]);
    acc[6]  = fmaf(wi, a1.z, acc[6]);  acc[7]  = fmaf(wi, a1.w, acc[7]);
    acc[8]  = fmaf(wi, a2.x, acc[8]);  acc[9]  = fmaf(wi, a2.y, acc[9]);
    acc[10] = fmaf(wi, a2.z, acc[10]); acc[11] = fmaf(wi, a2.w, acc[11]);
    acc[12] = fmaf(wi, a3.x, acc[12]); acc[13] = fmaf(wi, a3.y, acc[13]);
    acc[14] = fmaf(wi, a3.z, acc[14]); acc[15] = fmaf(wi, a3.w, acc[15]);
  }

  float dm[16], y[16], res[16];
  mk_dm(col, h, dm);
  const float scl = (float)(2.0/(EXP_B-EXP_A));
  const float shf = (float)((EXP_A+EXP_B)/(EXP_B-EXP_A));
#pragma unroll
  for (int i = 0; i < 16; ++i) y[i] = scl*acc[i] - shf*dm[i];
  F8 Yf[4];
  d2frags(y, lo_half, Yf);
  wave_clenshaw(cws + 32, NEXP, Yf, dm, lo_half, res);

  float* og = out + (size_t)bj*1024;
#pragma unroll
  for (int i = 0; i < 16; ++i) {
    int ro = (i & 3) + 8*(i >> 2) + 4*h;
    og[ro*32 + col] = res[i];
  }
}

extern "C" void kernel_launch(void* const* d_in, const int* in_sizes, int n_in,
                              void* d_out, int out_size, void* d_ws, size_t ws_size,
                              hipStream_t stream) {
  const float* X  = (const float*)d_in[0];
  const float* Wq = (const float*)d_in[1];
  const float* Wk = (const float*)d_in[2];
  const float* Wv = (const float*)d_in[3];
  float* out = (float*)d_out;
  float* ws  = (float*)d_ws;

  hipLaunchKernelGGL(k_coef,    dim3(1),    dim3(768), 0, stream, ws + WS_COEF);
  hipLaunchKernelGGL(k_logqkv,  dim3(1536), dim3(64),  0, stream, X, Wq, Wk, Wv, ws);
  hipLaunchKernelGGL(k_energy,  dim3(16),   dim3(256), 0, stream, ws);
  hipLaunchKernelGGL(k_meanexp, dim3(128),  dim3(256), 0, stream, ws, out);
}

// Round 7
// 74.790 us; speedup vs baseline: 1.8988x; 1.0010x over previous
//
#include <hip/hip_runtime.h>
#include <math.h>

// BS=8, M=64, D_IN=64, D_OUT=32; 512 tokens, 1536 (token,which) matrices.
#define NLOG 20
#define NEXP 14
#define LOG_A 0.9
#define LOG_B 7.0
#define EXP_A (-0.3)
#define EXP_B 2.1

// ws element-offset layout (all 16B-aligned)
#define WS_COEF 0            // [0..31] log coefs, [32..63] exp coefs
#define WS_NORM 64           // 1024 f32 (nQ[512], nK[512])
#define WS_WGT  1088         // 32768 f32 [bj][i]
#define WS_LV   33856        // 524288 f32: V-logs lane-major [token][lane*16+reg]
#define WS_QHI  558144       // 262144 u32 per plane
#define WS_QLO  820288
#define WS_KHI  1082432
#define WS_KLO  1344576      // ends 1606720 f32 = 6.43 MB

typedef float  f32x16 __attribute__((ext_vector_type(16)));
typedef short  short8 __attribute__((ext_vector_type(8)));
typedef unsigned int u32;

union F8 { short8 s; u32 u[4]; uint4 v; };

__device__ __forceinline__ u32 pkbf16(float a, float b) {
  u32 r;
  asm("v_cvt_pk_bf16_f32 %0, %1, %2" : "=v"(r) : "v"(a), "v"(b));
  return r;
}
__device__ __forceinline__ u32 xor32(u32 x) {
  return (u32)__shfl_xor((int)x, 32, 64);
}
__device__ __forceinline__ f32x16 MFMA(short8 a, short8 b, f32x16 c) {
  return __builtin_amdgcn_mfma_f32_32x32x16_bf16(a, b, c, 0, 0, 0);
}
#define Z16 {0.f,0.f,0.f,0.f,0.f,0.f,0.f,0.f,0.f,0.f,0.f,0.f,0.f,0.f,0.f,0.f}

// split 8 f32 into hi/lo bf16 fragments (pair-packed, element e -> k offset e)
__device__ __forceinline__ void pack8(const float* d, F8& hi, F8& lo) {
#pragma unroll
  for (int j = 0; j < 4; ++j) {
    float a = d[2*j], b = d[2*j+1];
    u32 hw = pkbf16(a, b);
    hi.u[j] = hw;
    float ha = __uint_as_float(hw << 16);
    float hb = __uint_as_float(hw & 0xffff0000u);
    lo.u[j] = pkbf16(a - ha, b - hb);
  }
}
__device__ __forceinline__ void packpairs(const float* d, u32* wh, u32* wl) {
  F8 a, b;
  pack8(d, a, b);
#pragma unroll
  for (int j = 0; j < 4; ++j) { wh[j] = a.u[j]; wl[j] = b.u[j]; }
  pack8(d + 8, a, b);
#pragma unroll
  for (int j = 0; j < 4; ++j) { wh[4+j] = a.u[j]; wl[4+j] = b.u[j]; }
}

// D-layout f32[16] (col=lane&31, row=(reg&3)+8*(reg>>2)+4*(lane>>5)) ->
// 4 frags: fr[0]=k0..15 hi, fr[1]=k0..15 lo, fr[2]=k16..31 hi, fr[3]=k16..31 lo.
__device__ __forceinline__ void d2frags(const float* d, int lo_half, F8 fr[4]) {
  u32 wh[8], wl[8];
  packpairs(d, wh, wl);
#pragma unroll
  for (int s = 0; s < 2; ++s) {
    const u32* w = s ? wl : wh;
    u32 c0=xor32(w[0]), c1=xor32(w[1]), c2=xor32(w[2]), c3=xor32(w[3]);
    u32 c4=xor32(w[4]), c5=xor32(w[5]), c6=xor32(w[6]), c7=xor32(w[7]);
    F8& f1 = fr[s];   F8& f2 = fr[2+s];
    f1.u[0] = lo_half ? w[0] : c2;
    f1.u[1] = lo_half ? w[1] : c3;
    f1.u[2] = lo_half ? c0   : w[2];
    f1.u[3] = lo_half ? c1   : w[3];
    f2.u[0] = lo_half ? w[4] : c6;
    f2.u[1] = lo_half ? w[5] : c7;
    f2.u[2] = lo_half ? c4   : w[6];
    f2.u[3] = lo_half ? c5   : w[7];
  }
}

__device__ __forceinline__ void mk_dm(int col, int h, float* dm) {
#pragma unroll
  for (int i = 0; i < 16; ++i) {
    int ro = (i & 3) + 8*(i >> 2) + 4*h;
    dm[i] = (ro == col) ? 1.f : 0.f;
  }
}

// res = p(Y) via Clenshaw; Yf = frags of symmetric Y; all state in D-layout regs.
__device__ __forceinline__ void wave_clenshaw(
    const float* __restrict__ coef, int nterms,
    const F8 Yf[4], const float* dm, int lo_half, float* res)
{
  float bc[16], bp[16];
  float cn = coef[nterms-1];
#pragma unroll
  for (int i = 0; i < 16; ++i) { bc[i] = cn*dm[i]; bp[i] = 0.f; }
  for (int kk = nterms-2; kk >= 1; --kk) {
    F8 bf[4];
    d2frags(bc, lo_half, bf);
    f32x16 acc = Z16;
    acc = MFMA(Yf[0].s, bf[0].s, acc);
    acc = MFMA(Yf[0].s, bf[1].s, acc);
    acc = MFMA(Yf[1].s, bf[0].s, acc);
    acc = MFMA(Yf[2].s, bf[2].s, acc);
    acc = MFMA(Yf[2].s, bf[3].s, acc);
    acc = MFMA(Yf[3].s, bf[2].s, acc);
    float ck = coef[kk];
#pragma unroll
    for (int i = 0; i < 16; ++i) {
      float nb = 2.f*acc[i] - bp[i] + ck*dm[i];
      bp[i] = bc[i]; bc[i] = nb;
    }
  }
  F8 bf[4];
  d2frags(bc, lo_half, bf);
  f32x16 acc = Z16;
  acc = MFMA(Yf[0].s, bf[0].s, acc);
  acc = MFMA(Yf[0].s, bf[1].s, acc);
  acc = MFMA(Yf[1].s, bf[0].s, acc);
  acc = MFMA(Yf[2].s, bf[2].s, acc);
  acc = MFMA(Yf[2].s, bf[3].s, acc);
  acc = MFMA(Yf[3].s, bf[2].s, acc);
  float c0h = 0.5f*coef[0];
#pragma unroll
  for (int i = 0; i < 16; ++i) res[i] = acc[i] - bp[i] + c0h*dm[i];
}

// ---------------- kernel 0: Chebyshev coefficients (parallel over terms) -------
__global__ __launch_bounds__(768) void k_coef(float* __restrict__ cws) {
  __shared__ double st[400];
  __shared__ double se[196];
  int t = threadIdx.x;
  const double PI = 3.14159265358979323846;
  if (t < 400) {
    int j = t / 20, k = t % 20;
    double th = PI*(k + 0.5)/20.0;
    st[t] = log(0.5*(LOG_A+LOG_B) + 0.5*(LOG_B-LOG_A)*cos(th)) * cos(j*th);
  }
  if (t >= 512 && t < 708) {
    int q = t - 512; int j = q / 14, k = q % 14;
    double th = PI*(k + 0.5)/14.0;
    se[q] = exp(0.5*(EXP_A+EXP_B) + 0.5*(EXP_B-EXP_A)*cos(th)) * cos(j*th);
  }
  __syncthreads();
  if (t < 20) {
    double s = 0.0;
    for (int k = 0; k < 20; ++k) s += st[t*20 + k];
    cws[t] = (float)(s / 10.0);           // 2s/20
  }
  if (t >= 32 && t < 46) {
    int j = t - 32; double s = 0.0;
    for (int k = 0; k < 14; ++k) s += se[j*14 + k];
    cws[32 + j] = (float)(s / 7.0);       // 2s/14
  }
}

// ---------------- kernel 1: S = W X W^T -> log(S), all MFMA, zero LDS ----------
// grid 1536 = 512 tokens x {Q,K,V}; 64 threads (1 wave).
__global__ __launch_bounds__(64, 2) void k_logqkv(
    const float* __restrict__ X, const float* __restrict__ Wq,
    const float* __restrict__ Wk, const float* __restrict__ Wv,
    float* __restrict__ ws)
{
  const float* cws = ws + WS_COEF;
  int gid = blockIdx.x;
  int token = gid / 3, which = gid - token*3;
  const float* W = (which == 0) ? Wq : ((which == 1) ? Wk : Wv);
  int l = threadIdx.x;
  int col = l & 31, h = l >> 5;
  int lo_half = (h == 0);

  // W fragments: Wf[2c]=hi, Wf[2c+1]=lo; slot value W[col][16c+8h+e]
  F8 Wf[8];
#pragma unroll
  for (int c = 0; c < 4; ++c) {
    const float* wp = W + col*64 + 16*c + 8*h;
    float d8[8];
    float4 v0 = *(const float4*)(wp);
    float4 v1 = *(const float4*)(wp + 4);
    d8[0]=v0.x; d8[1]=v0.y; d8[2]=v0.z; d8[3]=v0.w;
    d8[4]=v1.x; d8[5]=v1.y; d8[6]=v1.z; d8[7]=v1.w;
    pack8(d8, Wf[2*c], Wf[2*c+1]);
  }

  // U = X * W^T (64x32) as two 32-row blocks
  f32x16 Ua = Z16, Ub = Z16;
#pragma unroll
  for (int rb = 0; rb < 2; ++rb) {
#pragma unroll
    for (int c = 0; c < 4; ++c) {
      const float* xp = X + (size_t)token*4096 + (size_t)(col + 32*rb)*64 + 16*c + 8*h;
      float d8[8];
      float4 v0 = *(const float4*)(xp);
      float4 v1 = *(const float4*)(xp + 4);
      d8[0]=v0.x; d8[1]=v0.y; d8[2]=v0.z; d8[3]=v0.w;
      d8[4]=v1.x; d8[5]=v1.y; d8[6]=v1.z; d8[7]=v1.w;
      F8 xh, xl;
      pack8(d8, xh, xl);
      f32x16& U = rb ? Ub : Ua;
      U = MFMA(xh.s, Wf[2*c].s,   U);
      U = MFMA(xh.s, Wf[2*c+1].s, U);
      U = MFMA(xl.s, Wf[2*c].s,   U);
    }
  }

  // U (D-layout) -> B-frags for S-step: chunks 0..3 of K=64
  float ua[16], ub[16];
#pragma unroll
  for (int i = 0; i < 16; ++i) { ua[i] = Ua[i]; ub[i] = Ub[i]; }
  F8 Uf[8], t4[4];
  d2frags(ua, lo_half, t4);
  Uf[0]=t4[0]; Uf[1]=t4[1]; Uf[2]=t4[2]; Uf[3]=t4[3];
  d2frags(ub, lo_half, t4);
  Uf[4]=t4[0]; Uf[5]=t4[1]; Uf[6]=t4[2]; Uf[7]=t4[3];

  // S = W * U (32x32)
  f32x16 S = Z16;
#pragma unroll
  for (int c = 0; c < 4; ++c) {
    S = MFMA(Wf[2*c].s,   Uf[2*c].s,   S);
    S = MFMA(Wf[2*c].s,   Uf[2*c+1].s, S);
    S = MFMA(Wf[2*c+1].s, Uf[2*c].s,   S);
  }

  // affine map to Chebyshev domain, then log via Clenshaw
  float dm[16], y[16], res[16];
  mk_dm(col, h, dm);
  const float scl = (float)(2.0/(LOG_B-LOG_A));
  const float shf = (float)((LOG_A+LOG_B)/(LOG_B-LOG_A));
#pragma unroll
  for (int i = 0; i < 16; ++i) y[i] = scl*S[i] - shf*dm[i];
  F8 Yf[4];
  d2frags(y, lo_half, Yf);
  wave_clenshaw(cws, NLOG, Yf, dm, lo_half, res);

  if (which == 2) {
    float* LV = ws + WS_LV + (size_t)token*1024 + l*16;
#pragma unroll
    for (int g = 0; g < 4; ++g)
      *(float4*)(LV + 4*g) = make_float4(res[4*g], res[4*g+1], res[4*g+2], res[4*g+3]);
  } else {
    u32 wh[8], wl[8];
    packpairs(res, wh, wl);
    u32* hp = (u32*)ws + (which ? WS_KHI : WS_QHI) + (size_t)token*512 + l*8;
    u32* lp = (u32*)ws + (which ? WS_KLO : WS_QLO) + (size_t)token*512 + l*8;
    *(uint4*)(hp)     = make_uint4(wh[0], wh[1], wh[2], wh[3]);
    *(uint4*)(hp + 4) = make_uint4(wh[4], wh[5], wh[6], wh[7]);
    *(uint4*)(lp)     = make_uint4(wl[0], wl[1], wl[2], wl[3]);
    *(uint4*)(lp + 4) = make_uint4(wl[4], wl[5], wl[6], wl[7]);
    float nrm = 0.f;
#pragma unroll
    for (int i = 0; i < 16; ++i) nrm += res[i]*res[i];
#pragma unroll
    for (int off = 32; off >= 1; off >>= 1) nrm += __shfl_xor(nrm, off, 64);
    if (l == 0) ws[WS_NORM + which*512 + token] = nrm;
  }
}

// ---------------- kernel 2: Gram via MFMA + energies + softmax -> weights ------
// grid 16 = 8 b x 2 jt(32 j each); 256 threads = 4 waves (rb = w&1, kh = w>>1).
__global__ __launch_bounds__(256) void k_energy(float* __restrict__ ws)
{
  __shared__ float sG[2][32][68];
  __shared__ float sS[32][68];
  __shared__ float sMax[32], sInv[32];
  const u32* Qhi = (const u32*)ws + WS_QHI;
  const u32* Qlo = (const u32*)ws + WS_QLO;
  const u32* Khi = (const u32*)ws + WS_KHI;
  const u32* Klo = (const u32*)ws + WS_KLO;
  const float* norms = ws + WS_NORM;
  float* wgt = ws + WS_WGT;

  int b = blockIdx.x >> 1, j0 = (blockIdx.x & 1)*32;
  int t = threadIdx.x;
  int w = t >> 6, l = t & 63;
  int rb = w & 1, kh = w >> 1;
  int col = l & 31, h = l >> 5;
  int itok = b*64 + rb*32 + col;   // A rows: K-logs
  int jtok = b*64 + j0 + col;      // B cols: Q-logs

  const u32* Ah = Khi + (size_t)itok*512;
  const u32* Al = Klo + (size_t)itok*512;
  const u32* Bh = Qhi + (size_t)jtok*512;
  const u32* Bl = Qlo + (size_t)jtok*512;

  f32x16 acc = Z16;
  for (int c = kh*32; c < kh*32 + 32; ++c) {
    int off = 8*c + 4*h;
    F8 ah, al, bh, bl;
    ah.v = *(const uint4*)(Ah + off);
    al.v = *(const uint4*)(Al + off);
    bh.v = *(const uint4*)(Bh + off);
    bl.v = *(const uint4*)(Bl + off);
    acc = MFMA(ah.s, bh.s, acc);
    acc = MFMA(ah.s, bl.s, acc);
    acc = MFMA(al.s, bh.s, acc);
  }
#pragma unroll
  for (int g = 0; g < 4; ++g) {
    int ro = rb*32 + 8*g + 4*h;
    *(float4*)(&sG[kh][col][ro]) = make_float4(acc[4*g], acc[4*g+1], acc[4*g+2], acc[4*g+3]);
  }
  __syncthreads();

  int j = t & 31, ig = t >> 5;
  float nq = norms[b*64 + j0 + j];
#pragma unroll
  for (int i = ig*8; i < ig*8 + 8; ++i) {
    float g = sG[0][j][i] + sG[1][j][i];
    float e = fmaxf(norms[512 + b*64 + i] + nq - 2.f*g, 0.f);
    sS[j][i] = 1.f/(1.f + log1pf(e));
  }
  __syncthreads();
  if (t < 32) {
    float m = -1e30f;
    for (int i = 0; i < 64; ++i) m = fmaxf(m, sS[t][i]);
    float s = 0.f;
    for (int i = 0; i < 64; ++i) s += expf(sS[t][i] - m);
    sMax[t] = m; sInv[t] = 1.f/s;
  }
  __syncthreads();
  float m = sMax[j], inv = sInv[j];
#pragma unroll
  for (int i = ig*8; i < ig*8 + 8; ++i)
    wgt[(size_t)(b*64 + j0 + j)*64 + i] = expf(sS[j][i] - m)*inv;
}

// ---------------- kernel 3: weighted log-mean + matrix exp (MFMA Clenshaw) -----
// grid 128; 256 threads = 4 waves, wave = one (b,j).
__global__ __launch_bounds__(256, 2) void k_meanexp(
    const float* __restrict__ ws_c, float* __restrict__ out)
{
  __shared__ float sW[4][64];
  const float* cws = ws_c + WS_COEF;
  const float* LV  = ws_c + WS_LV;
  const float* wgt = ws_c + WS_WGT;

  int wv = threadIdx.x >> 6, l = threadIdx.x & 63;
  int bj = blockIdx.x*4 + wv;
  int b = bj >> 6;
  int col = l & 31, h = l >> 5;
  int lo_half = (h == 0);

  sW[wv][l] = wgt[(size_t)bj*64 + l];   // intra-wave LDS: in-order, no barrier

  float acc[16];
#pragma unroll
  for (int i = 0; i < 16; ++i) acc[i] = 0.f;
  const float* vb = LV + (size_t)b*65536 + l*16;
  for (int i = 0; i < 64; ++i) {
    float wi = sW[wv][i];
    const float* vp = vb + (size_t)i*1024;
    float4 a0 = *(const float4*)(vp);
    float4 a1 = *(const float4*)(vp + 4);
    float4 a2 = *(const float4*)(vp + 8);
    float4 a3 = *(const float4*)(vp + 12);
    acc[0]  = fmaf(wi, a0.x, acc[0]);  acc[1]  = fmaf(wi, a0.y, acc[1]);
    acc[2]  = fmaf(wi, a0.z, acc[2]);  acc[3]  = fmaf(wi, a0.w, acc[3]);
    acc[4]  = fmaf(wi, a1.x, acc[4]);  acc[5]  = fmaf(wi, a1.y, acc[5]);
    acc[6]  = fmaf(wi, a1.z, acc[6]);  acc[7]  = fmaf(wi, a1.w, acc[7]);
    acc[8]  = fmaf(wi, a2.x, acc[8]);  acc[9]  = fmaf(wi, a2.y, acc[9]);
    acc[10] = fmaf(wi, a2.z, acc[10]); acc[11] = fmaf(wi, a2.w, acc[11]);
    acc[12] = fmaf(wi, a3.x, acc[12]); acc[13] = fmaf(wi, a3.y, acc[13]);
    acc[14] = fmaf(wi, a3.z, acc[14]); acc[15] = fmaf(wi, a3.w, acc[15]);
  }

  float dm[16], y[16], res[16];
  mk_dm(col, h, dm);
  const float scl = (float)(2.0/(EXP_B-EXP_A));
  const float shf = (float)((EXP_A+EXP_B)/(EXP_B-EXP_A));
#pragma unroll
  for (int i = 0; i < 16; ++i) y[i] = scl*acc[i] - shf*dm[i];
  F8 Yf[4];
  d2frags(y, lo_half, Yf);
  wave_clenshaw(cws + 32, NEXP, Yf, dm, lo_half, res);

  float* og = out + (size_t)bj*1024;
#pragma unroll
  for (int i = 0; i < 16; ++i) {
    int ro = (i & 3) + 8*(i >> 2) + 4*h;
    og[ro*32 + col] = res[i];
  }
}

extern "C" void kernel_launch(void* const* d_in, const int* in_sizes, int n_in,
                              void* d_out, int out_size, void* d_ws, size_t ws_size,
                              hipStream_t stream) {
  const float* X  = (const float*)d_in[0];
  const float* Wq = (const float*)d_in[1];
  const float* Wk = (const float*)d_in[2];
  const float* Wv = (const float*)d_in[3];
  float* out = (float*)d_out;
  float* ws  = (float*)d_ws;

  hipLaunchKernelGGL(k_coef,    dim3(1),    dim3(768), 0, stream, ws + WS_COEF);
  hipLaunchKernelGGL(k_logqkv,  dim3(1536), dim3(64),  0, stream, X, Wq, Wk, Wv, ws);
  hipLaunchKernelGGL(k_energy,  dim3(16),   dim3(256), 0, stream, ws);
  hipLaunchKernelGGL(k_meanexp, dim3(128),  dim3(256), 0, stream, ws, out);
}

// Round 8
// 69.724 us; speedup vs baseline: 2.0368x; 1.0727x over previous
//
#include <hip/hip_runtime.h>
#include <math.h>

// BS=8, M=64, D_IN=64, D_OUT=32; 512 tokens, 1536 (token,which) matrices.
#define NLOG 20
#define NEXP 14
#define LOG_A 0.9
#define LOG_B 7.0
#define EXP_A (-0.3)
#define EXP_B 2.1

// ws element-offset layout (all 16B-aligned)
#define WS_NORM 64           // 1024 f32 (nQ[512], nK[512])
#define WS_WGT  1088         // 32768 f32 [bj][i]
#define WS_LV   33856        // 524288 f32: V-logs lane-major [token][lane*16+reg]
#define WS_QHI  558144       // 262144 u32 per plane
#define WS_QLO  820288
#define WS_KHI  1082432
#define WS_KLO  1344576      // ends 1606720 f32 = 6.43 MB

// Exact Chebyshev coefficients (closed-form, verified at both interval ends):
// log on [0.9,7]:  c0 = 2 ln C, c_k = -2 t^k / k,  t = -0.4721377, C = 3.2299892
//   check: p(1)=1.9459099 (ln7=1.9459101), p(-1)=-0.1053612 (ln0.9=-0.1053605)
// exp on [-0.3,2.1]: c_k = 2 e^0.9 I_k(1.2)
//   check: p(1)=8.1661712 (e^2.1=8.1661699), p(-1)=0.7408175 (e^-0.3=0.7408182)
__device__ __constant__ float LOGC[NLOG] = {
  2.3449578f,  0.9442755f, -0.2229140f,  0.0701641f, -0.0248454f,
  0.0093843f, -0.0036923f,  0.0014942f, -0.0006173f,  0.0002591f,
 -0.0001101f,  4.725e-05f, -2.045e-05f,  8.914e-06f, -3.907e-06f,
  1.722e-06f, -7.620e-07f,  3.390e-07f, -1.510e-07f,  6.760e-08f
};
__device__ __constant__ float EXPC[NEXP] = {
  6.8560235f,  3.5156490f,  0.9966101f,  0.1936152f,  0.0285348f,
  0.0033839f,  3.355e-04f,  2.856e-05f,  2.131e-06f,  1.415e-07f,
  8.470e-09f,  4.610e-10f,  2.240e-11f,  1.030e-12f
};

typedef float  f32x16 __attribute__((ext_vector_type(16)));
typedef short  short8 __attribute__((ext_vector_type(8)));
typedef unsigned int u32;

union F8 { short8 s; u32 u[4]; uint4 v; };

__device__ __forceinline__ u32 pkbf16(float a, float b) {
  u32 r;
  asm("v_cvt_pk_bf16_f32 %0, %1, %2" : "=v"(r) : "v"(a), "v"(b));
  return r;
}
__device__ __forceinline__ u32 xor32(u32 x) {
  return (u32)__shfl_xor((int)x, 32, 64);
}
__device__ __forceinline__ f32x16 MFMA(short8 a, short8 b, f32x16 c) {
  return __builtin_amdgcn_mfma_f32_32x32x16_bf16(a, b, c, 0, 0, 0);
}
#define Z16 {0.f,0.f,0.f,0.f,0.f,0.f,0.f,0.f,0.f,0.f,0.f,0.f,0.f,0.f,0.f,0.f}

// split 8 f32 into hi/lo bf16 fragments (pair-packed, element e -> k offset e)
__device__ __forceinline__ void pack8(const float* d, F8& hi, F8& lo) {
#pragma unroll
  for (int j = 0; j < 4; ++j) {
    float a = d[2*j], b = d[2*j+1];
    u32 hw = pkbf16(a, b);
    hi.u[j] = hw;
    float ha = __uint_as_float(hw << 16);
    float hb = __uint_as_float(hw & 0xffff0000u);
    lo.u[j] = pkbf16(a - ha, b - hb);
  }
}
__device__ __forceinline__ void packpairs(const float* d, u32* wh, u32* wl) {
  F8 a, b;
  pack8(d, a, b);
#pragma unroll
  for (int j = 0; j < 4; ++j) { wh[j] = a.u[j]; wl[j] = b.u[j]; }
  pack8(d + 8, a, b);
#pragma unroll
  for (int j = 0; j < 4; ++j) { wh[4+j] = a.u[j]; wl[4+j] = b.u[j]; }
}

// D-layout f32[16] (col=lane&31, row=(reg&3)+8*(reg>>2)+4*(lane>>5)) ->
// 4 frags: fr[0]=k0..15 hi, fr[1]=k0..15 lo, fr[2]=k16..31 hi, fr[3]=k16..31 lo.
__device__ __forceinline__ void d2frags(const float* d, int lo_half, F8 fr[4]) {
  u32 wh[8], wl[8];
  packpairs(d, wh, wl);
#pragma unroll
  for (int s = 0; s < 2; ++s) {
    const u32* w = s ? wl : wh;
    u32 c0=xor32(w[0]), c1=xor32(w[1]), c2=xor32(w[2]), c3=xor32(w[3]);
    u32 c4=xor32(w[4]), c5=xor32(w[5]), c6=xor32(w[6]), c7=xor32(w[7]);
    F8& f1 = fr[s];   F8& f2 = fr[2+s];
    f1.u[0] = lo_half ? w[0] : c2;
    f1.u[1] = lo_half ? w[1] : c3;
    f1.u[2] = lo_half ? c0   : w[2];
    f1.u[3] = lo_half ? c1   : w[3];
    f2.u[0] = lo_half ? w[4] : c6;
    f2.u[1] = lo_half ? w[5] : c7;
    f2.u[2] = lo_half ? c4   : w[6];
    f2.u[3] = lo_half ? c5   : w[7];
  }
}

__device__ __forceinline__ void mk_dm(int col, int h, float* dm) {
#pragma unroll
  for (int i = 0; i < 16; ++i) {
    int ro = (i & 3) + 8*(i >> 2) + 4*h;
    dm[i] = (ro == col) ? 1.f : 0.f;
  }
}

// res = p(Y) via Clenshaw; Yf = frags of symmetric Y; all state in D-layout regs.
__device__ __forceinline__ void wave_clenshaw(
    const float* __restrict__ coef, int nterms,
    const F8 Yf[4], const float* dm, int lo_half, float* res)
{
  float bc[16], bp[16];
  float cn = coef[nterms-1];
#pragma unroll
  for (int i = 0; i < 16; ++i) { bc[i] = cn*dm[i]; bp[i] = 0.f; }
  for (int kk = nterms-2; kk >= 1; --kk) {
    F8 bf[4];
    d2frags(bc, lo_half, bf);
    f32x16 acc = Z16;
    acc = MFMA(Yf[0].s, bf[0].s, acc);
    acc = MFMA(Yf[0].s, bf[1].s, acc);
    acc = MFMA(Yf[1].s, bf[0].s, acc);
    acc = MFMA(Yf[2].s, bf[2].s, acc);
    acc = MFMA(Yf[2].s, bf[3].s, acc);
    acc = MFMA(Yf[3].s, bf[2].s, acc);
    float ck = coef[kk];
#pragma unroll
    for (int i = 0; i < 16; ++i) {
      float nb = 2.f*acc[i] - bp[i] + ck*dm[i];
      bp[i] = bc[i]; bc[i] = nb;
    }
  }
  F8 bf[4];
  d2frags(bc, lo_half, bf);
  f32x16 acc = Z16;
  acc = MFMA(Yf[0].s, bf[0].s, acc);
  acc = MFMA(Yf[0].s, bf[1].s, acc);
  acc = MFMA(Yf[1].s, bf[0].s, acc);
  acc = MFMA(Yf[2].s, bf[2].s, acc);
  acc = MFMA(Yf[2].s, bf[3].s, acc);
  acc = MFMA(Yf[3].s, bf[2].s, acc);
  float c0h = 0.5f*coef[0];
#pragma unroll
  for (int i = 0; i < 16; ++i) res[i] = acc[i] - bp[i] + c0h*dm[i];
}

// ---------------- kernel 1: S = W X W^T -> log(S), all MFMA, zero LDS ----------
// grid 1536 = 512 tokens x {Q,K,V}; 64 threads (1 wave).
__global__ __launch_bounds__(64, 2) void k_logqkv(
    const float* __restrict__ X, const float* __restrict__ Wq,
    const float* __restrict__ Wk, const float* __restrict__ Wv,
    float* __restrict__ ws)
{
  int gid = blockIdx.x;
  int token = gid / 3, which = gid - token*3;
  const float* W = (which == 0) ? Wq : ((which == 1) ? Wk : Wv);
  int l = threadIdx.x;
  int col = l & 31, h = l >> 5;
  int lo_half = (h == 0);

  // W fragments: Wf[2c]=hi, Wf[2c+1]=lo; slot value W[col][16c+8h+e]
  F8 Wf[8];
#pragma unroll
  for (int c = 0; c < 4; ++c) {
    const float* wp = W + col*64 + 16*c + 8*h;
    float d8[8];
    float4 v0 = *(const float4*)(wp);
    float4 v1 = *(const float4*)(wp + 4);
    d8[0]=v0.x; d8[1]=v0.y; d8[2]=v0.z; d8[3]=v0.w;
    d8[4]=v1.x; d8[5]=v1.y; d8[6]=v1.z; d8[7]=v1.w;
    pack8(d8, Wf[2*c], Wf[2*c+1]);
  }

  // U = X * W^T (64x32) as two 32-row blocks
  f32x16 Ua = Z16, Ub = Z16;
#pragma unroll
  for (int rb = 0; rb < 2; ++rb) {
#pragma unroll
    for (int c = 0; c < 4; ++c) {
      const float* xp = X + (size_t)token*4096 + (size_t)(col + 32*rb)*64 + 16*c + 8*h;
      float d8[8];
      float4 v0 = *(const float4*)(xp);
      float4 v1 = *(const float4*)(xp + 4);
      d8[0]=v0.x; d8[1]=v0.y; d8[2]=v0.z; d8[3]=v0.w;
      d8[4]=v1.x; d8[5]=v1.y; d8[6]=v1.z; d8[7]=v1.w;
      F8 xh, xl;
      pack8(d8, xh, xl);
      f32x16& U = rb ? Ub : Ua;
      U = MFMA(xh.s, Wf[2*c].s,   U);
      U = MFMA(xh.s, Wf[2*c+1].s, U);
      U = MFMA(xl.s, Wf[2*c].s,   U);
    }
  }

  // U (D-layout) -> B-frags for S-step: chunks 0..3 of K=64
  float ua[16], ub[16];
#pragma unroll
  for (int i = 0; i < 16; ++i) { ua[i] = Ua[i]; ub[i] = Ub[i]; }
  F8 Uf[8], t4[4];
  d2frags(ua, lo_half, t4);
  Uf[0]=t4[0]; Uf[1]=t4[1]; Uf[2]=t4[2]; Uf[3]=t4[3];
  d2frags(ub, lo_half, t4);
  Uf[4]=t4[0]; Uf[5]=t4[1]; Uf[6]=t4[2]; Uf[7]=t4[3];

  // S = W * U (32x32)
  f32x16 S = Z16;
#pragma unroll
  for (int c = 0; c < 4; ++c) {
    S = MFMA(Wf[2*c].s,   Uf[2*c].s,   S);
    S = MFMA(Wf[2*c].s,   Uf[2*c+1].s, S);
    S = MFMA(Wf[2*c+1].s, Uf[2*c].s,   S);
  }

  // affine map to Chebyshev domain, then log via Clenshaw
  float dm[16], y[16], res[16];
  mk_dm(col, h, dm);
  const float scl = (float)(2.0/(LOG_B-LOG_A));
  const float shf = (float)((LOG_A+LOG_B)/(LOG_B-LOG_A));
#pragma unroll
  for (int i = 0; i < 16; ++i) y[i] = scl*S[i] - shf*dm[i];
  F8 Yf[4];
  d2frags(y, lo_half, Yf);
  wave_clenshaw(LOGC, NLOG, Yf, dm, lo_half, res);

  if (which == 2) {
    float* LV = ws + WS_LV + (size_t)token*1024 + l*16;
#pragma unroll
    for (int g = 0; g < 4; ++g)
      *(float4*)(LV + 4*g) = make_float4(res[4*g], res[4*g+1], res[4*g+2], res[4*g+3]);
  } else {
    u32 wh[8], wl[8];
    packpairs(res, wh, wl);
    u32* hp = (u32*)ws + (which ? WS_KHI : WS_QHI) + (size_t)token*512 + l*8;
    u32* lp = (u32*)ws + (which ? WS_KLO : WS_QLO) + (size_t)token*512 + l*8;
    *(uint4*)(hp)     = make_uint4(wh[0], wh[1], wh[2], wh[3]);
    *(uint4*)(hp + 4) = make_uint4(wh[4], wh[5], wh[6], wh[7]);
    *(uint4*)(lp)     = make_uint4(wl[0], wl[1], wl[2], wl[3]);
    *(uint4*)(lp + 4) = make_uint4(wl[4], wl[5], wl[6], wl[7]);
    float nrm = 0.f;
#pragma unroll
    for (int i = 0; i < 16; ++i) nrm += res[i]*res[i];
#pragma unroll
    for (int off = 32; off >= 1; off >>= 1) nrm += __shfl_xor(nrm, off, 64);
    if (l == 0) ws[WS_NORM + which*512 + token] = nrm;
  }
}

// ---------------- kernel 2: Gram via MFMA + energies + softmax -> weights ------
// grid 16 = 8 b x 2 jt(32 j each); 256 threads = 4 waves (rb = w&1, kh = w>>1).
__global__ __launch_bounds__(256) void k_energy(float* __restrict__ ws)
{
  __shared__ float sG[2][32][68];
  __shared__ float sS[32][68];
  __shared__ float sMax[32], sInv[32];
  const u32* Qhi = (const u32*)ws + WS_QHI;
  const u32* Qlo = (const u32*)ws + WS_QLO;
  const u32* Khi = (const u32*)ws + WS_KHI;
  const u32* Klo = (const u32*)ws + WS_KLO;
  const float* norms = ws + WS_NORM;
  float* wgt = ws + WS_WGT;

  int b = blockIdx.x >> 1, j0 = (blockIdx.x & 1)*32;
  int t = threadIdx.x;
  int w = t >> 6, l = t & 63;
  int rb = w & 1, kh = w >> 1;
  int col = l & 31, h = l >> 5;
  int itok = b*64 + rb*32 + col;   // A rows: K-logs
  int jtok = b*64 + j0 + col;      // B cols: Q-logs

  const u32* Ah = Khi + (size_t)itok*512;
  const u32* Al = Klo + (size_t)itok*512;
  const u32* Bh = Qhi + (size_t)jtok*512;
  const u32* Bl = Qlo + (size_t)jtok*512;

  f32x16 acc = Z16;
  for (int c = kh*32; c < kh*32 + 32; ++c) {
    int off = 8*c + 4*h;
    F8 ah, al, bh, bl;
    ah.v = *(const uint4*)(Ah + off);
    al.v = *(const uint4*)(Al + off);
    bh.v = *(const uint4*)(Bh + off);
    bl.v = *(const uint4*)(Bl + off);
    acc = MFMA(ah.s, bh.s, acc);
    acc = MFMA(ah.s, bl.s, acc);
    acc = MFMA(al.s, bh.s, acc);
  }
#pragma unroll
  for (int g = 0; g < 4; ++g) {
    int ro = rb*32 + 8*g + 4*h;
    *(float4*)(&sG[kh][col][ro]) = make_float4(acc[4*g], acc[4*g+1], acc[4*g+2], acc[4*g+3]);
  }
  __syncthreads();

  int j = t & 31, ig = t >> 5;
  float nq = norms[b*64 + j0 + j];
#pragma unroll
  for (int i = ig*8; i < ig*8 + 8; ++i) {
    float g = sG[0][j][i] + sG[1][j][i];
    float e = fmaxf(norms[512 + b*64 + i] + nq - 2.f*g, 0.f);
    sS[j][i] = 1.f/(1.f + log1pf(e));
  }
  __syncthreads();
  if (t < 32) {
    float m = -1e30f;
    for (int i = 0; i < 64; ++i) m = fmaxf(m, sS[t][i]);
    float s = 0.f;
    for (int i = 0; i < 64; ++i) s += expf(sS[t][i] - m);
    sMax[t] = m; sInv[t] = 1.f/s;
  }
  __syncthreads();
  float m = sMax[j], inv = sInv[j];
#pragma unroll
  for (int i = ig*8; i < ig*8 + 8; ++i)
    wgt[(size_t)(b*64 + j0 + j)*64 + i] = expf(sS[j][i] - m)*inv;
}

// ---------------- kernel 3: weighted log-mean + matrix exp (MFMA Clenshaw) -----
// grid 128; 256 threads = 4 waves, wave = one (b,j).
__global__ __launch_bounds__(256, 2) void k_meanexp(
    const float* __restrict__ ws_c, float* __restrict__ out)
{
  __shared__ float sW[4][64];
  const float* LV  = ws_c + WS_LV;
  const float* wgt = ws_c + WS_WGT;

  int wv = threadIdx.x >> 6, l = threadIdx.x & 63;
  int bj = blockIdx.x*4 + wv;
  int b = bj >> 6;
  int col = l & 31, h = l >> 5;
  int lo_half = (h == 0);

  sW[wv][l] = wgt[(size_t)bj*64 + l];   // intra-wave LDS: in-order, no barrier

  float acc[16];
#pragma unroll
  for (int i = 0; i < 16; ++i) acc[i] = 0.f;
  const float* vb = LV + (size_t)b*65536 + l*16;
  for (int i = 0; i < 64; ++i) {
    float wi = sW[wv][i];
    const float* vp = vb + (size_t)i*1024;
    float4 a0 = *(const float4*)(vp);
    float4 a1 = *(const float4*)(vp + 4);
    float4 a2 = *(const float4*)(vp + 8);
    float4 a3 = *(const float4*)(vp + 12);
    acc[0]  = fmaf(wi, a0.x, acc[0]);  acc[1]  = fmaf(wi, a0.y, acc[1]);
    acc[2]  = fmaf(wi, a0.z, acc[2]);  acc[3]  = fmaf(wi, a0.w, acc[3]);
    acc[4]  = fmaf(wi, a1.x, acc[4]);  acc[5]  = fmaf(wi, a1.y, acc[5]);
    acc[6]  = fmaf(wi, a1.z, acc[6]);  acc[7]  = fmaf(wi, a1.w, acc[7]);
    acc[8]  = fmaf(wi, a2.x, acc[8]);  acc[9]  = fmaf(wi, a2.y, acc[9]);
    acc[10] = fmaf(wi, a2.z, acc[10]); acc[11] = fmaf(wi, a2.w, acc[11]);
    acc[12] = fmaf(wi, a3.x, acc[12]); acc[13] = fmaf(wi, a3.y, acc[13]);
    acc[14] = fmaf(wi, a3.z, acc[14]); acc[15] = fmaf(wi, a3.w, acc[15]);
  }

  float dm[16], y[16], res[16];
  mk_dm(col, h, dm);
  const float scl = (float)(2.0/(EXP_B-EXP_A));
  const float shf = (float)((EXP_A+EXP_B)/(EXP_B-EXP_A));
#pragma unroll
  for (int i = 0; i < 16; ++i) y[i] = scl*acc[i] - shf*dm[i];
  F8 Yf[4];
  d2frags(y, lo_half, Yf);
  wave_clenshaw(EXPC, NEXP, Yf, dm, lo_half, res);

  float* og = out + (size_t)bj*1024;
#pragma unroll
  for (int i = 0; i < 16; ++i) {
    int ro = (i & 3) + 8*(i >> 2) + 4*h;
    og[ro*32 + col] = res[i];
  }
}

extern "C" void kernel_launch(void* const* d_in, const int* in_sizes, int n_in,
                              void* d_out, int out_size, void* d_ws, size_t ws_size,
                              hipStream_t stream) {
  const float* X  = (const float*)d_in[0];
  const float* Wq = (const float*)d_in[1];
  const float* Wk = (const float*)d_in[2];
  const float* Wv = (const float*)d_in[3];
  float* out = (float*)d_out;
  float* ws  = (float*)d_ws;

  hipLaunchKernelGGL(k_logqkv,  dim3(1536), dim3(64),  0, stream, X, Wq, Wk, Wv, ws);
  hipLaunchKernelGGL(k_energy,  dim3(16),   dim3(256), 0, stream, ws);
  hipLaunchKernelGGL(k_meanexp, dim3(128),  dim3(256), 0, stream, ws, out);
}

// Round 10
// 66.053 us; speedup vs baseline: 2.1500x; 1.0556x over previous
//
#include <hip/hip_runtime.h>
#include <math.h>

// BS=8, M=64, D_IN=64, D_OUT=32; 512 tokens, 1536 (token,which) matrices.
// Structure: byte-identical to the R8 pass (69.7us). SINGLE DELTA: NLOG 20->16,
// NEXP 14->10 (data-only; tails 1.2e-6 / 8.5e-9, far below bf16 noise 0.018).
// wave_clenshaw inner loop is FROZEN: R3/R4/R5/R6/R9 all failed on
// semantically-equivalent rewrites of it (0.219/0.367 signatures).
#define NLOG 16
#define NEXP 10
#define LOG_A 0.9
#define LOG_B 7.0
#define EXP_A (-0.3)
#define EXP_B 2.1

// ws element-offset layout (all 16B-aligned)
#define WS_NORM 64           // 1024 f32 (nQ[512], nK[512])
#define WS_WGT  1088         // 32768 f32 [bj][i]
#define WS_LV   33856        // 524288 f32: V-logs lane-major [token][lane*16+reg]
#define WS_QHI  558144       // 262144 u32 per plane
#define WS_QLO  820288
#define WS_KHI  1082432
#define WS_KLO  1344576      // ends 1606720 f32 = 6.43 MB

// Exact Chebyshev coefficients (closed-form, verified at both interval ends):
// log on [0.9,7]:  c0 = 2 ln C, c_k = -2 t^k / k,  t = -0.4721377, C = 3.2299892
// exp on [-0.3,2.1]: c_k = 2 e^0.9 I_k(1.2)
__device__ __constant__ float LOGC[NLOG] = {
  2.3449578f,  0.9442755f, -0.2229140f,  0.0701641f, -0.0248454f,
  0.0093843f, -0.0036923f,  0.0014942f, -0.0006173f,  0.0002591f,
 -0.0001101f,  4.725e-05f, -2.045e-05f,  8.914e-06f, -3.907e-06f,
  1.722e-06f
};
__device__ __constant__ float EXPC[NEXP] = {
  6.8560235f,  3.5156490f,  0.9966101f,  0.1936152f,  0.0285348f,
  0.0033839f,  3.355e-04f,  2.856e-05f,  2.131e-06f,  1.415e-07f
};

typedef float  f32x16 __attribute__((ext_vector_type(16)));
typedef short  short8 __attribute__((ext_vector_type(8)));
typedef unsigned int u32;

union F8 { short8 s; u32 u[4]; uint4 v; };

__device__ __forceinline__ u32 pkbf16(float a, float b) {
  u32 r;
  asm("v_cvt_pk_bf16_f32 %0, %1, %2" : "=v"(r) : "v"(a), "v"(b));
  return r;
}
__device__ __forceinline__ u32 xor32(u32 x) {
  return (u32)__shfl_xor((int)x, 32, 64);
}
__device__ __forceinline__ f32x16 MFMA(short8 a, short8 b, f32x16 c) {
  return __builtin_amdgcn_mfma_f32_32x32x16_bf16(a, b, c, 0, 0, 0);
}
#define Z16 {0.f,0.f,0.f,0.f,0.f,0.f,0.f,0.f,0.f,0.f,0.f,0.f,0.f,0.f,0.f,0.f}

// split 8 f32 into hi/lo bf16 fragments (pair-packed, element e -> k offset e)
__device__ __forceinline__ void pack8(const float* d, F8& hi, F8& lo) {
#pragma unroll
  for (int j = 0; j < 4; ++j) {
    float a = d[2*j], b = d[2*j+1];
    u32 hw = pkbf16(a, b);
    hi.u[j] = hw;
    float ha = __uint_as_float(hw << 16);
    float hb = __uint_as_float(hw & 0xffff0000u);
    lo.u[j] = pkbf16(a - ha, b - hb);
  }
}
__device__ __forceinline__ void packpairs(const float* d, u32* wh, u32* wl) {
  F8 a, b;
  pack8(d, a, b);
#pragma unroll
  for (int j = 0; j < 4; ++j) { wh[j] = a.u[j]; wl[j] = b.u[j]; }
  pack8(d + 8, a, b);
#pragma unroll
  for (int j = 0; j < 4; ++j) { wh[4+j] = a.u[j]; wl[4+j] = b.u[j]; }
}

// D-layout f32[16] (col=lane&31, row=(reg&3)+8*(reg>>2)+4*(lane>>5)) ->
// 4 frags: fr[0]=k0..15 hi, fr[1]=k0..15 lo, fr[2]=k16..31 hi, fr[3]=k16..31 lo.
__device__ __forceinline__ void d2frags(const float* d, int lo_half, F8 fr[4]) {
  u32 wh[8], wl[8];
  packpairs(d, wh, wl);
#pragma unroll
  for (int s = 0; s < 2; ++s) {
    const u32* w = s ? wl : wh;
    u32 c0=xor32(w[0]), c1=xor32(w[1]), c2=xor32(w[2]), c3=xor32(w[3]);
    u32 c4=xor32(w[4]), c5=xor32(w[5]), c6=xor32(w[6]), c7=xor32(w[7]);
    F8& f1 = fr[s];   F8& f2 = fr[2+s];
    f1.u[0] = lo_half ? w[0] : c2;
    f1.u[1] = lo_half ? w[1] : c3;
    f1.u[2] = lo_half ? c0   : w[2];
    f1.u[3] = lo_half ? c1   : w[3];
    f2.u[0] = lo_half ? w[4] : c6;
    f2.u[1] = lo_half ? w[5] : c7;
    f2.u[2] = lo_half ? c4   : w[6];
    f2.u[3] = lo_half ? c5   : w[7];
  }
}

__device__ __forceinline__ void mk_dm(int col, int h, float* dm) {
#pragma unroll
  for (int i = 0; i < 16; ++i) {
    int ro = (i & 3) + 8*(i >> 2) + 4*h;
    dm[i] = (ro == col) ? 1.f : 0.f;
  }
}

// res = p(Y) via Clenshaw; Yf = frags of symmetric Y; all state in D-layout regs.
// FROZEN structure (R2/R7/R8-verified). Do not reorder/split the MFMA chain.
__device__ __forceinline__ void wave_clenshaw(
    const float* __restrict__ coef, int nterms,
    const F8 Yf[4], const float* dm, int lo_half, float* res)
{
  float bc[16], bp[16];
  float cn = coef[nterms-1];
#pragma unroll
  for (int i = 0; i < 16; ++i) { bc[i] = cn*dm[i]; bp[i] = 0.f; }
  for (int kk = nterms-2; kk >= 1; --kk) {
    F8 bf[4];
    d2frags(bc, lo_half, bf);
    f32x16 acc = Z16;
    acc = MFMA(Yf[0].s, bf[0].s, acc);
    acc = MFMA(Yf[0].s, bf[1].s, acc);
    acc = MFMA(Yf[1].s, bf[0].s, acc);
    acc = MFMA(Yf[2].s, bf[2].s, acc);
    acc = MFMA(Yf[2].s, bf[3].s, acc);
    acc = MFMA(Yf[3].s, bf[2].s, acc);
    float ck = coef[kk];
#pragma unroll
    for (int i = 0; i < 16; ++i) {
      float nb = 2.f*acc[i] - bp[i] + ck*dm[i];
      bp[i] = bc[i]; bc[i] = nb;
    }
  }
  F8 bf[4];
  d2frags(bc, lo_half, bf);
  f32x16 acc = Z16;
  acc = MFMA(Yf[0].s, bf[0].s, acc);
  acc = MFMA(Yf[0].s, bf[1].s, acc);
  acc = MFMA(Yf[1].s, bf[0].s, acc);
  acc = MFMA(Yf[2].s, bf[2].s, acc);
  acc = MFMA(Yf[2].s, bf[3].s, acc);
  acc = MFMA(Yf[3].s, bf[2].s, acc);
  float c0h = 0.5f*coef[0];
#pragma unroll
  for (int i = 0; i < 16; ++i) res[i] = acc[i] - bp[i] + c0h*dm[i];
}

// ---------------- kernel 1: S = W X W^T -> log(S), all MFMA, zero LDS ----------
// grid 1536 = 512 tokens x {Q,K,V}; 64 threads (1 wave).
__global__ __launch_bounds__(64, 2) void k_logqkv(
    const float* __restrict__ X, const float* __restrict__ Wq,
    const float* __restrict__ Wk, const float* __restrict__ Wv,
    float* __restrict__ ws)
{
  int gid = blockIdx.x;
  int token = gid / 3, which = gid - token*3;
  const float* W = (which == 0) ? Wq : ((which == 1) ? Wk : Wv);
  int l = threadIdx.x;
  int col = l & 31, h = l >> 5;
  int lo_half = (h == 0);

  // W fragments: Wf[2c]=hi, Wf[2c+1]=lo; slot value W[col][16c+8h+e]
  F8 Wf[8];
#pragma unroll
  for (int c = 0; c < 4; ++c) {
    const float* wp = W + col*64 + 16*c + 8*h;
    float d8[8];
    float4 v0 = *(const float4*)(wp);
    float4 v1 = *(const float4*)(wp + 4);
    d8[0]=v0.x; d8[1]=v0.y; d8[2]=v0.z; d8[3]=v0.w;
    d8[4]=v1.x; d8[5]=v1.y; d8[6]=v1.z; d8[7]=v1.w;
    pack8(d8, Wf[2*c], Wf[2*c+1]);
  }

  // U = X * W^T (64x32) as two 32-row blocks
  f32x16 Ua = Z16, Ub = Z16;
#pragma unroll
  for (int rb = 0; rb < 2; ++rb) {
#pragma unroll
    for (int c = 0; c < 4; ++c) {
      const float* xp = X + (size_t)token*4096 + (size_t)(col + 32*rb)*64 + 16*c + 8*h;
      float d8[8];
      float4 v0 = *(const float4*)(xp);
      float4 v1 = *(const float4*)(xp + 4);
      d8[0]=v0.x; d8[1]=v0.y; d8[2]=v0.z; d8[3]=v0.w;
      d8[4]=v1.x; d8[5]=v1.y; d8[6]=v1.z; d8[7]=v1.w;
      F8 xh, xl;
      pack8(d8, xh, xl);
      f32x16& U = rb ? Ub : Ua;
      U = MFMA(xh.s, Wf[2*c].s,   U);
      U = MFMA(xh.s, Wf[2*c+1].s, U);
      U = MFMA(xl.s, Wf[2*c].s,   U);
    }
  }

  // U (D-layout) -> B-frags for S-step: chunks 0..3 of K=64
  float ua[16], ub[16];
#pragma unroll
  for (int i = 0; i < 16; ++i) { ua[i] = Ua[i]; ub[i] = Ub[i]; }
  F8 Uf[8], t4[4];
  d2frags(ua, lo_half, t4);
  Uf[0]=t4[0]; Uf[1]=t4[1]; Uf[2]=t4[2]; Uf[3]=t4[3];
  d2frags(ub, lo_half, t4);
  Uf[4]=t4[0]; Uf[5]=t4[1]; Uf[6]=t4[2]; Uf[7]=t4[3];

  // S = W * U (32x32)
  f32x16 S = Z16;
#pragma unroll
  for (int c = 0; c < 4; ++c) {
    S = MFMA(Wf[2*c].s,   Uf[2*c].s,   S);
    S = MFMA(Wf[2*c].s,   Uf[2*c+1].s, S);
    S = MFMA(Wf[2*c+1].s, Uf[2*c].s,   S);
  }

  // affine map to Chebyshev domain, then log via Clenshaw
  float dm[16], y[16], res[16];
  mk_dm(col, h, dm);
  const float scl = (float)(2.0/(LOG_B-LOG_A));
  const float shf = (float)((LOG_A+LOG_B)/(LOG_B-LOG_A));
#pragma unroll
  for (int i = 0; i < 16; ++i) y[i] = scl*S[i] - shf*dm[i];
  F8 Yf[4];
  d2frags(y, lo_half, Yf);
  wave_clenshaw(LOGC, NLOG, Yf, dm, lo_half, res);

  if (which == 2) {
    float* LV = ws + WS_LV + (size_t)token*1024 + l*16;
#pragma unroll
    for (int g = 0; g < 4; ++g)
      *(float4*)(LV + 4*g) = make_float4(res[4*g], res[4*g+1], res[4*g+2], res[4*g+3]);
  } else {
    u32 wh[8], wl[8];
    packpairs(res, wh, wl);
    u32* hp = (u32*)ws + (which ? WS_KHI : WS_QHI) + (size_t)token*512 + l*8;
    u32* lp = (u32*)ws + (which ? WS_KLO : WS_QLO) + (size_t)token*512 + l*8;
    *(uint4*)(hp)     = make_uint4(wh[0], wh[1], wh[2], wh[3]);
    *(uint4*)(hp + 4) = make_uint4(wh[4], wh[5], wh[6], wh[7]);
    *(uint4*)(lp)     = make_uint4(wl[0], wl[1], wl[2], wl[3]);
    *(uint4*)(lp + 4) = make_uint4(wl[4], wl[5], wl[6], wl[7]);
    float nrm = 0.f;
#pragma unroll
    for (int i = 0; i < 16; ++i) nrm += res[i]*res[i];
#pragma unroll
    for (int off = 32; off >= 1; off >>= 1) nrm += __shfl_xor(nrm, off, 64);
    if (l == 0) ws[WS_NORM + which*512 + token] = nrm;
  }
}

// ---------------- kernel 2: Gram via MFMA + energies + softmax -> weights ------
// grid 16 = 8 b x 2 jt(32 j each); 256 threads = 4 waves (rb = w&1, kh = w>>1).
__global__ __launch_bounds__(256) void k_energy(float* __restrict__ ws)
{
  __shared__ float sG[2][32][68];
  __shared__ float sS[32][68];
  __shared__ float sMax[32], sInv[32];
  const u32* Qhi = (const u32*)ws + WS_QHI;
  const u32* Qlo = (const u32*)ws + WS_QLO;
  const u32* Khi = (const u32*)ws + WS_KHI;
  const u32* Klo = (const u32*)ws + WS_KLO;
  const float* norms = ws + WS_NORM;
  float* wgt = ws + WS_WGT;

  int b = blockIdx.x >> 1, j0 = (blockIdx.x & 1)*32;
  int t = threadIdx.x;
  int w = t >> 6, l = t & 63;
  int rb = w & 1, kh = w >> 1;
  int col = l & 31, h = l >> 5;
  int itok = b*64 + rb*32 + col;   // A rows: K-logs
  int jtok = b*64 + j0 + col;      // B cols: Q-logs

  const u32* Ah = Khi + (size_t)itok*512;
  const u32* Al = Klo + (size_t)itok*512;
  const u32* Bh = Qhi + (size_t)jtok*512;
  const u32* Bl = Qlo + (size_t)jtok*512;

  f32x16 acc = Z16;
  for (int c = kh*32; c < kh*32 + 32; ++c) {
    int off = 8*c + 4*h;
    F8 ah, al, bh, bl;
    ah.v = *(const uint4*)(Ah + off);
    al.v = *(const uint4*)(Al + off);
    bh.v = *(const uint4*)(Bh + off);
    bl.v = *(const uint4*)(Bl + off);
    acc = MFMA(ah.s, bh.s, acc);
    acc = MFMA(ah.s, bl.s, acc);
    acc = MFMA(al.s, bh.s, acc);
  }
#pragma unroll
  for (int g = 0; g < 4; ++g) {
    int ro = rb*32 + 8*g + 4*h;
    *(float4*)(&sG[kh][col][ro]) = make_float4(acc[4*g], acc[4*g+1], acc[4*g+2], acc[4*g+3]);
  }
  __syncthreads();

  int j = t & 31, ig = t >> 5;
  float nq = norms[b*64 + j0 + j];
#pragma unroll
  for (int i = ig*8; i < ig*8 + 8; ++i) {
    float g = sG[0][j][i] + sG[1][j][i];
    float e = fmaxf(norms[512 + b*64 + i] + nq - 2.f*g, 0.f);
    sS[j][i] = 1.f/(1.f + log1pf(e));
  }
  __syncthreads();
  if (t < 32) {
    float m = -1e30f;
    for (int i = 0; i < 64; ++i) m = fmaxf(m, sS[t][i]);
    float s = 0.f;
    for (int i = 0; i < 64; ++i) s += expf(sS[t][i] - m);
    sMax[t] = m; sInv[t] = 1.f/s;
  }
  __syncthreads();
  float m = sMax[j], inv = sInv[j];
#pragma unroll
  for (int i = ig*8; i < ig*8 + 8; ++i)
    wgt[(size_t)(b*64 + j0 + j)*64 + i] = expf(sS[j][i] - m)*inv;
}

// ---------------- kernel 3: weighted log-mean + matrix exp (MFMA Clenshaw) -----
// grid 128; 256 threads = 4 waves, wave = one (b,j).
__global__ __launch_bounds__(256, 2) void k_meanexp(
    const float* __restrict__ ws_c, float* __restrict__ out)
{
  __shared__ float sW[4][64];
  const float* LV  = ws_c + WS_LV;
  const float* wgt = ws_c + WS_WGT;

  int wv = threadIdx.x >> 6, l = threadIdx.x & 63;
  int bj = blockIdx.x*4 + wv;
  int b = bj >> 6;
  int col = l & 31, h = l >> 5;
  int lo_half = (h == 0);

  sW[wv][l] = wgt[(size_t)bj*64 + l];   // intra-wave LDS: in-order, no barrier

  float acc[16];
#pragma unroll
  for (int i = 0; i < 16; ++i) acc[i] = 0.f;
  const float* vb = LV + (size_t)b*65536 + l*16;
  for (int i = 0; i < 64; ++i) {
    float wi = sW[wv][i];
    const float* vp = vb + (size_t)i*1024;
    float4 a0 = *(const float4*)(vp);
    float4 a1 = *(const float4*)(vp + 4);
    float4 a2 = *(const float4*)(vp + 8);
    float4 a3 = *(const float4*)(vp + 12);
    acc[0]  = fmaf(wi, a0.x, acc[0]);  acc[1]  = fmaf(wi, a0.y, acc[1]);
    acc[2]  = fmaf(wi, a0.z, acc[2]);  acc[3]  = fmaf(wi, a0.w, acc[3]);
    acc[4]  = fmaf(wi, a1.x, acc[4]);  acc[5]  = fmaf(wi, a1.y, acc[5]);
    acc[6]  = fmaf(wi, a1.z, acc[6]);  acc[7]  = fmaf(wi, a1.w, acc[7]);
    acc[8]  = fmaf(wi, a2.x, acc[8]);  acc[9]  = fmaf(wi, a2.y, acc[9]);
    acc[10] = fmaf(wi, a2.z, acc[10]); acc[11] = fmaf(wi, a2.w, acc[11]);
    acc[12] = fmaf(wi, a3.x, acc[12]); acc[13] = fmaf(wi, a3.y, acc[13]);
    acc[14] = fmaf(wi, a3.z, acc[14]); acc[15] = fmaf(wi, a3.w, acc[15]);
  }

  float dm[16], y[16], res[16];
  mk_dm(col, h, dm);
  const float scl = (float)(2.0/(EXP_B-EXP_A));
  const float shf = (float)((EXP_A+EXP_B)/(EXP_B-EXP_A));
#pragma unroll
  for (int i = 0; i < 16; ++i) y[i] = scl*acc[i] - shf*dm[i];
  F8 Yf[4];
  d2frags(y, lo_half, Yf);
  wave_clenshaw(EXPC, NEXP, Yf, dm, lo_half, res);

  float* og = out + (size_t)bj*1024;
#pragma unroll
  for (int i = 0; i < 16; ++i) {
    int ro = (i & 3) + 8*(i >> 2) + 4*h;
    og[ro*32 + col] = res[i];
  }
}

extern "C" void kernel_launch(void* const* d_in, const int* in_sizes, int n_in,
                              void* d_out, int out_size, void* d_ws, size_t ws_size,
                              hipStream_t stream) {
  const float* X  = (const float*)d_in[0];
  const float* Wq = (const float*)d_in[1];
  const float* Wk = (const float*)d_in[2];
  const float* Wv = (const float*)d_in[3];
  float* out = (float*)d_out;
  float* ws  = (float*)d_ws;

  hipLaunchKernelGGL(k_logqkv,  dim3(1536), dim3(64),  0, stream, X, Wq, Wk, Wv, ws);
  hipLaunchKernelGGL(k_energy,  dim3(16),   dim3(256), 0, stream, ws);
  hipLaunchKernelGGL(k_meanexp, dim3(128),  dim3(256), 0, stream, ws, out);
}

// Round 11
// 65.912 us; speedup vs baseline: 2.1546x; 1.0021x over previous
//
#include <hip/hip_runtime.h>
#include <math.h>

// BS=8, M=64, D_IN=64, D_OUT=32; 512 tokens, 1536 (token,which) matrices.
// Anchor: R10 pass (66.05us, absmax 0.0182). SINGLE DELTA vs R10:
// '#pragma unroll 4' on k_meanexp's i-loop (latency hiding; FP order unchanged).
// wave_clenshaw inner loop is FROZEN: R3/R4/R5/R6/R9 all failed on
// semantically-equivalent rewrites of it (0.219/0.367 signatures).
#define NLOG 16
#define NEXP 10
#define LOG_A 0.9
#define LOG_B 7.0
#define EXP_A (-0.3)
#define EXP_B 2.1

// ws element-offset layout (all 16B-aligned)
#define WS_NORM 64           // 1024 f32 (nQ[512], nK[512])
#define WS_WGT  1088         // 32768 f32 [bj][i]
#define WS_LV   33856        // 524288 f32: V-logs lane-major [token][lane*16+reg]
#define WS_QHI  558144       // 262144 u32 per plane
#define WS_QLO  820288
#define WS_KHI  1082432
#define WS_KLO  1344576      // ends 1606720 f32 = 6.43 MB

// Exact Chebyshev coefficients (closed-form, verified at both interval ends):
// log on [0.9,7]:  c0 = 2 ln C, c_k = -2 t^k / k,  t = -0.4721377, C = 3.2299892
// exp on [-0.3,2.1]: c_k = 2 e^0.9 I_k(1.2)
__device__ __constant__ float LOGC[NLOG] = {
  2.3449578f,  0.9442755f, -0.2229140f,  0.0701641f, -0.0248454f,
  0.0093843f, -0.0036923f,  0.0014942f, -0.0006173f,  0.0002591f,
 -0.0001101f,  4.725e-05f, -2.045e-05f,  8.914e-06f, -3.907e-06f,
  1.722e-06f
};
__device__ __constant__ float EXPC[NEXP] = {
  6.8560235f,  3.5156490f,  0.9966101f,  0.1936152f,  0.0285348f,
  0.0033839f,  3.355e-04f,  2.856e-05f,  2.131e-06f,  1.415e-07f
};

typedef float  f32x16 __attribute__((ext_vector_type(16)));
typedef short  short8 __attribute__((ext_vector_type(8)));
typedef unsigned int u32;

union F8 { short8 s; u32 u[4]; uint4 v; };

__device__ __forceinline__ u32 pkbf16(float a, float b) {
  u32 r;
  asm("v_cvt_pk_bf16_f32 %0, %1, %2" : "=v"(r) : "v"(a), "v"(b));
  return r;
}
__device__ __forceinline__ u32 xor32(u32 x) {
  return (u32)__shfl_xor((int)x, 32, 64);
}
__device__ __forceinline__ f32x16 MFMA(short8 a, short8 b, f32x16 c) {
  return __builtin_amdgcn_mfma_f32_32x32x16_bf16(a, b, c, 0, 0, 0);
}
#define Z16 {0.f,0.f,0.f,0.f,0.f,0.f,0.f,0.f,0.f,0.f,0.f,0.f,0.f,0.f,0.f,0.f}

// split 8 f32 into hi/lo bf16 fragments (pair-packed, element e -> k offset e)
__device__ __forceinline__ void pack8(const float* d, F8& hi, F8& lo) {
#pragma unroll
  for (int j = 0; j < 4; ++j) {
    float a = d[2*j], b = d[2*j+1];
    u32 hw = pkbf16(a, b);
    hi.u[j] = hw;
    float ha = __uint_as_float(hw << 16);
    float hb = __uint_as_float(hw & 0xffff0000u);
    lo.u[j] = pkbf16(a - ha, b - hb);
  }
}
__device__ __forceinline__ void packpairs(const float* d, u32* wh, u32* wl) {
  F8 a, b;
  pack8(d, a, b);
#pragma unroll
  for (int j = 0; j < 4; ++j) { wh[j] = a.u[j]; wl[j] = b.u[j]; }
  pack8(d + 8, a, b);
#pragma unroll
  for (int j = 0; j < 4; ++j) { wh[4+j] = a.u[j]; wl[4+j] = b.u[j]; }
}

// D-layout f32[16] (col=lane&31, row=(reg&3)+8*(reg>>2)+4*(lane>>5)) ->
// 4 frags: fr[0]=k0..15 hi, fr[1]=k0..15 lo, fr[2]=k16..31 hi, fr[3]=k16..31 lo.
__device__ __forceinline__ void d2frags(const float* d, int lo_half, F8 fr[4]) {
  u32 wh[8], wl[8];
  packpairs(d, wh, wl);
#pragma unroll
  for (int s = 0; s < 2; ++s) {
    const u32* w = s ? wl : wh;
    u32 c0=xor32(w[0]), c1=xor32(w[1]), c2=xor32(w[2]), c3=xor32(w[3]);
    u32 c4=xor32(w[4]), c5=xor32(w[5]), c6=xor32(w[6]), c7=xor32(w[7]);
    F8& f1 = fr[s];   F8& f2 = fr[2+s];
    f1.u[0] = lo_half ? w[0] : c2;
    f1.u[1] = lo_half ? w[1] : c3;
    f1.u[2] = lo_half ? c0   : w[2];
    f1.u[3] = lo_half ? c1   : w[3];
    f2.u[0] = lo_half ? w[4] : c6;
    f2.u[1] = lo_half ? w[5] : c7;
    f2.u[2] = lo_half ? c4   : w[6];
    f2.u[3] = lo_half ? c5   : w[7];
  }
}

__device__ __forceinline__ void mk_dm(int col, int h, float* dm) {
#pragma unroll
  for (int i = 0; i < 16; ++i) {
    int ro = (i & 3) + 8*(i >> 2) + 4*h;
    dm[i] = (ro == col) ? 1.f : 0.f;
  }
}

// res = p(Y) via Clenshaw; Yf = frags of symmetric Y; all state in D-layout regs.
// FROZEN structure (R2/R7/R8/R10-verified). Do not reorder/split the MFMA chain.
__device__ __forceinline__ void wave_clenshaw(
    const float* __restrict__ coef, int nterms,
    const F8 Yf[4], const float* dm, int lo_half, float* res)
{
  float bc[16], bp[16];
  float cn = coef[nterms-1];
#pragma unroll
  for (int i = 0; i < 16; ++i) { bc[i] = cn*dm[i]; bp[i] = 0.f; }
  for (int kk = nterms-2; kk >= 1; --kk) {
    F8 bf[4];
    d2frags(bc, lo_half, bf);
    f32x16 acc = Z16;
    acc = MFMA(Yf[0].s, bf[0].s, acc);
    acc = MFMA(Yf[0].s, bf[1].s, acc);
    acc = MFMA(Yf[1].s, bf[0].s, acc);
    acc = MFMA(Yf[2].s, bf[2].s, acc);
    acc = MFMA(Yf[2].s, bf[3].s, acc);
    acc = MFMA(Yf[3].s, bf[2].s, acc);
    float ck = coef[kk];
#pragma unroll
    for (int i = 0; i < 16; ++i) {
      float nb = 2.f*acc[i] - bp[i] + ck*dm[i];
      bp[i] = bc[i]; bc[i] = nb;
    }
  }
  F8 bf[4];
  d2frags(bc, lo_half, bf);
  f32x16 acc = Z16;
  acc = MFMA(Yf[0].s, bf[0].s, acc);
  acc = MFMA(Yf[0].s, bf[1].s, acc);
  acc = MFMA(Yf[1].s, bf[0].s, acc);
  acc = MFMA(Yf[2].s, bf[2].s, acc);
  acc = MFMA(Yf[2].s, bf[3].s, acc);
  acc = MFMA(Yf[3].s, bf[2].s, acc);
  float c0h = 0.5f*coef[0];
#pragma unroll
  for (int i = 0; i < 16; ++i) res[i] = acc[i] - bp[i] + c0h*dm[i];
}

// ---------------- kernel 1: S = W X W^T -> log(S), all MFMA, zero LDS ----------
// grid 1536 = 512 tokens x {Q,K,V}; 64 threads (1 wave).
__global__ __launch_bounds__(64, 2) void k_logqkv(
    const float* __restrict__ X, const float* __restrict__ Wq,
    const float* __restrict__ Wk, const float* __restrict__ Wv,
    float* __restrict__ ws)
{
  int gid = blockIdx.x;
  int token = gid / 3, which = gid - token*3;
  const float* W = (which == 0) ? Wq : ((which == 1) ? Wk : Wv);
  int l = threadIdx.x;
  int col = l & 31, h = l >> 5;
  int lo_half = (h == 0);

  // W fragments: Wf[2c]=hi, Wf[2c+1]=lo; slot value W[col][16c+8h+e]
  F8 Wf[8];
#pragma unroll
  for (int c = 0; c < 4; ++c) {
    const float* wp = W + col*64 + 16*c + 8*h;
    float d8[8];
    float4 v0 = *(const float4*)(wp);
    float4 v1 = *(const float4*)(wp + 4);
    d8[0]=v0.x; d8[1]=v0.y; d8[2]=v0.z; d8[3]=v0.w;
    d8[4]=v1.x; d8[5]=v1.y; d8[6]=v1.z; d8[7]=v1.w;
    pack8(d8, Wf[2*c], Wf[2*c+1]);
  }

  // U = X * W^T (64x32) as two 32-row blocks
  f32x16 Ua = Z16, Ub = Z16;
#pragma unroll
  for (int rb = 0; rb < 2; ++rb) {
#pragma unroll
    for (int c = 0; c < 4; ++c) {
      const float* xp = X + (size_t)token*4096 + (size_t)(col + 32*rb)*64 + 16*c + 8*h;
      float d8[8];
      float4 v0 = *(const float4*)(xp);
      float4 v1 = *(const float4*)(xp + 4);
      d8[0]=v0.x; d8[1]=v0.y; d8[2]=v0.z; d8[3]=v0.w;
      d8[4]=v1.x; d8[5]=v1.y; d8[6]=v1.z; d8[7]=v1.w;
      F8 xh, xl;
      pack8(d8, xh, xl);
      f32x16& U = rb ? Ub : Ua;
      U = MFMA(xh.s, Wf[2*c].s,   U);
      U = MFMA(xh.s, Wf[2*c+1].s, U);
      U = MFMA(xl.s, Wf[2*c].s,   U);
    }
  }

  // U (D-layout) -> B-frags for S-step: chunks 0..3 of K=64
  float ua[16], ub[16];
#pragma unroll
  for (int i = 0; i < 16; ++i) { ua[i] = Ua[i]; ub[i] = Ub[i]; }
  F8 Uf[8], t4[4];
  d2frags(ua, lo_half, t4);
  Uf[0]=t4[0]; Uf[1]=t4[1]; Uf[2]=t4[2]; Uf[3]=t4[3];
  d2frags(ub, lo_half, t4);
  Uf[4]=t4[0]; Uf[5]=t4[1]; Uf[6]=t4[2]; Uf[7]=t4[3];

  // S = W * U (32x32)
  f32x16 S = Z16;
#pragma unroll
  for (int c = 0; c < 4; ++c) {
    S = MFMA(Wf[2*c].s,   Uf[2*c].s,   S);
    S = MFMA(Wf[2*c].s,   Uf[2*c+1].s, S);
    S = MFMA(Wf[2*c+1].s, Uf[2*c].s,   S);
  }

  // affine map to Chebyshev domain, then log via Clenshaw
  float dm[16], y[16], res[16];
  mk_dm(col, h, dm);
  const float scl = (float)(2.0/(LOG_B-LOG_A));
  const float shf = (float)((LOG_A+LOG_B)/(LOG_B-LOG_A));
#pragma unroll
  for (int i = 0; i < 16; ++i) y[i] = scl*S[i] - shf*dm[i];
  F8 Yf[4];
  d2frags(y, lo_half, Yf);
  wave_clenshaw(LOGC, NLOG, Yf, dm, lo_half, res);

  if (which == 2) {
    float* LV = ws + WS_LV + (size_t)token*1024 + l*16;
#pragma unroll
    for (int g = 0; g < 4; ++g)
      *(float4*)(LV + 4*g) = make_float4(res[4*g], res[4*g+1], res[4*g+2], res[4*g+3]);
  } else {
    u32 wh[8], wl[8];
    packpairs(res, wh, wl);
    u32* hp = (u32*)ws + (which ? WS_KHI : WS_QHI) + (size_t)token*512 + l*8;
    u32* lp = (u32*)ws + (which ? WS_KLO : WS_QLO) + (size_t)token*512 + l*8;
    *(uint4*)(hp)     = make_uint4(wh[0], wh[1], wh[2], wh[3]);
    *(uint4*)(hp + 4) = make_uint4(wh[4], wh[5], wh[6], wh[7]);
    *(uint4*)(lp)     = make_uint4(wl[0], wl[1], wl[2], wl[3]);
    *(uint4*)(lp + 4) = make_uint4(wl[4], wl[5], wl[6], wl[7]);
    float nrm = 0.f;
#pragma unroll
    for (int i = 0; i < 16; ++i) nrm += res[i]*res[i];
#pragma unroll
    for (int off = 32; off >= 1; off >>= 1) nrm += __shfl_xor(nrm, off, 64);
    if (l == 0) ws[WS_NORM + which*512 + token] = nrm;
  }
}

// ---------------- kernel 2: Gram via MFMA + energies + softmax -> weights ------
// grid 16 = 8 b x 2 jt(32 j each); 256 threads = 4 waves (rb = w&1, kh = w>>1).
__global__ __launch_bounds__(256) void k_energy(float* __restrict__ ws)
{
  __shared__ float sG[2][32][68];
  __shared__ float sS[32][68];
  __shared__ float sMax[32], sInv[32];
  const u32* Qhi = (const u32*)ws + WS_QHI;
  const u32* Qlo = (const u32*)ws + WS_QLO;
  const u32* Khi = (const u32*)ws + WS_KHI;
  const u32* Klo = (const u32*)ws + WS_KLO;
  const float* norms = ws + WS_NORM;
  float* wgt = ws + WS_WGT;

  int b = blockIdx.x >> 1, j0 = (blockIdx.x & 1)*32;
  int t = threadIdx.x;
  int w = t >> 6, l = t & 63;
  int rb = w & 1, kh = w >> 1;
  int col = l & 31, h = l >> 5;
  int itok = b*64 + rb*32 + col;   // A rows: K-logs
  int jtok = b*64 + j0 + col;      // B cols: Q-logs

  const u32* Ah = Khi + (size_t)itok*512;
  const u32* Al = Klo + (size_t)itok*512;
  const u32* Bh = Qhi + (size_t)jtok*512;
  const u32* Bl = Qlo + (size_t)jtok*512;

  f32x16 acc = Z16;
  for (int c = kh*32; c < kh*32 + 32; ++c) {
    int off = 8*c + 4*h;
    F8 ah, al, bh, bl;
    ah.v = *(const uint4*)(Ah + off);
    al.v = *(const uint4*)(Al + off);
    bh.v = *(const uint4*)(Bh + off);
    bl.v = *(const uint4*)(Bl + off);
    acc = MFMA(ah.s, bh.s, acc);
    acc = MFMA(ah.s, bl.s, acc);
    acc = MFMA(al.s, bh.s, acc);
  }
#pragma unroll
  for (int g = 0; g < 4; ++g) {
    int ro = rb*32 + 8*g + 4*h;
    *(float4*)(&sG[kh][col][ro]) = make_float4(acc[4*g], acc[4*g+1], acc[4*g+2], acc[4*g+3]);
  }
  __syncthreads();

  int j = t & 31, ig = t >> 5;
  float nq = norms[b*64 + j0 + j];
#pragma unroll
  for (int i = ig*8; i < ig*8 + 8; ++i) {
    float g = sG[0][j][i] + sG[1][j][i];
    float e = fmaxf(norms[512 + b*64 + i] + nq - 2.f*g, 0.f);
    sS[j][i] = 1.f/(1.f + log1pf(e));
  }
  __syncthreads();
  if (t < 32) {
    float m = -1e30f;
    for (int i = 0; i < 64; ++i) m = fmaxf(m, sS[t][i]);
    float s = 0.f;
    for (int i = 0; i < 64; ++i) s += expf(sS[t][i] - m);
    sMax[t] = m; sInv[t] = 1.f/s;
  }
  __syncthreads();
  float m = sMax[j], inv = sInv[j];
#pragma unroll
  for (int i = ig*8; i < ig*8 + 8; ++i)
    wgt[(size_t)(b*64 + j0 + j)*64 + i] = expf(sS[j][i] - m)*inv;
}

// ---------------- kernel 3: weighted log-mean + matrix exp (MFMA Clenshaw) -----
// grid 128; 256 threads = 4 waves, wave = one (b,j).
__global__ __launch_bounds__(256, 2) void k_meanexp(
    const float* __restrict__ ws_c, float* __restrict__ out)
{
  __shared__ float sW[4][64];
  const float* LV  = ws_c + WS_LV;
  const float* wgt = ws_c + WS_WGT;

  int wv = threadIdx.x >> 6, l = threadIdx.x & 63;
  int bj = blockIdx.x*4 + wv;
  int b = bj >> 6;
  int col = l & 31, h = l >> 5;
  int lo_half = (h == 0);

  sW[wv][l] = wgt[(size_t)bj*64 + l];   // intra-wave LDS: in-order, no barrier

  float acc[16];
#pragma unroll
  for (int i = 0; i < 16; ++i) acc[i] = 0.f;
  const float* vb = LV + (size_t)b*65536 + l*16;
#pragma unroll 4
  for (int i = 0; i < 64; ++i) {
    float wi = sW[wv][i];
    const float* vp = vb + (size_t)i*1024;
    float4 a0 = *(const float4*)(vp);
    float4 a1 = *(const float4*)(vp + 4);
    float4 a2 = *(const float4*)(vp + 8);
    float4 a3 = *(const float4*)(vp + 12);
    acc[0]  = fmaf(wi, a0.x, acc[0]);  acc[1]  = fmaf(wi, a0.y, acc[1]);
    acc[2]  = fmaf(wi, a0.z, acc[2]);  acc[3]  = fmaf(wi, a0.w, acc[3]);
    acc[4]  = fmaf(wi, a1.x, acc[4]);  acc[5]  = fmaf(wi, a1.y, acc[5]);
    acc[6]  = fmaf(wi, a1.z, acc[6]);  acc[7]  = fmaf(wi, a1.w, acc[7]);
    acc[8]  = fmaf(wi, a2.x, acc[8]);  acc[9]  = fmaf(wi, a2.y, acc[9]);
    acc[10] = fmaf(wi, a2.z, acc[10]); acc[11] = fmaf(wi, a2.w, acc[11]);
    acc[12] = fmaf(wi, a3.x, acc[12]); acc[13] = fmaf(wi, a3.y, acc[13]);
    acc[14] = fmaf(wi, a3.z, acc[14]); acc[15] = fmaf(wi, a3.w, acc[15]);
  }

  float dm[16], y[16], res[16];
  mk_dm(col, h, dm);
  const float scl = (float)(2.0/(EXP_B-EXP_A));
  const float shf = (float)((EXP_A+EXP_B)/(EXP_B-EXP_A));
#pragma unroll
  for (int i = 0; i < 16; ++i) y[i] = scl*acc[i] - shf*dm[i];
  F8 Yf[4];
  d2frags(y, lo_half, Yf);
  wave_clenshaw(EXPC, NEXP, Yf, dm, lo_half, res);

  float* og = out + (size_t)bj*1024;
#pragma unroll
  for (int i = 0; i < 16; ++i) {
    int ro = (i & 3) + 8*(i >> 2) + 4*h;
    og[ro*32 + col] = res[i];
  }
}

extern "C" void kernel_launch(void* const* d_in, const int* in_sizes, int n_in,
                              void* d_out, int out_size, void* d_ws, size_t ws_size,
                              hipStream_t stream) {
  const float* X  = (const float*)d_in[0];
  const float* Wq = (const float*)d_in[1];
  const float* Wk = (const float*)d_in[2];
  const float* Wv = (const float*)d_in[3];
  float* out = (float*)d_out;
  float* ws  = (float*)d_ws;

  hipLaunchKernelGGL(k_logqkv,  dim3(1536), dim3(64),  0, stream, X, Wq, Wk, Wv, ws);
  hipLaunchKernelGGL(k_energy,  dim3(16),   dim3(256), 0, stream, ws);
  hipLaunchKernelGGL(k_meanexp, dim3(128),  dim3(256), 0, stream, ws, out);
}

// Round 12
// 64.060 us; speedup vs baseline: 2.2169x; 1.0289x over previous
//
#include <hip/hip_runtime.h>
#include <math.h>

// BS=8, M=64, D_IN=64, D_OUT=32; 512 tokens, 1536 (token,which) matrices.
// Anchor: R11 pass (65.91us, absmax 0.0178). SINGLE DELTA vs R11:
// NLOG 16->14, NEXP 10->8 (data-only; tails 7.5e-6 / 2.3e-6, far below the
// 0.018 bf16 noise floor; same proven-safe axis as R10).
// wave_clenshaw inner loop is FROZEN: R3/R4/R5/R6/R9 all failed on
// semantically-equivalent rewrites of it (0.219/0.367 signatures).
#define NLOG 14
#define NEXP 8
#define LOG_A 0.9
#define LOG_B 7.0
#define EXP_A (-0.3)
#define EXP_B 2.1

// ws element-offset layout (all 16B-aligned)
#define WS_NORM 64           // 1024 f32 (nQ[512], nK[512])
#define WS_WGT  1088         // 32768 f32 [bj][i]
#define WS_LV   33856        // 524288 f32: V-logs lane-major [token][lane*16+reg]
#define WS_QHI  558144       // 262144 u32 per plane
#define WS_QLO  820288
#define WS_KHI  1082432
#define WS_KLO  1344576      // ends 1606720 f32 = 6.43 MB

// Exact Chebyshev coefficients (closed-form, verified at both interval ends):
// log on [0.9,7]:  c0 = 2 ln C, c_k = -2 t^k / k,  t = -0.4721377, C = 3.2299892
// exp on [-0.3,2.1]: c_k = 2 e^0.9 I_k(1.2)
__device__ __constant__ float LOGC[NLOG] = {
  2.3449578f,  0.9442755f, -0.2229140f,  0.0701641f, -0.0248454f,
  0.0093843f, -0.0036923f,  0.0014942f, -0.0006173f,  0.0002591f,
 -0.0001101f,  4.725e-05f, -2.045e-05f,  8.914e-06f
};
__device__ __constant__ float EXPC[NEXP] = {
  6.8560235f,  3.5156490f,  0.9966101f,  0.1936152f,  0.0285348f,
  0.0033839f,  3.355e-04f,  2.856e-05f
};

typedef float  f32x16 __attribute__((ext_vector_type(16)));
typedef short  short8 __attribute__((ext_vector_type(8)));
typedef unsigned int u32;

union F8 { short8 s; u32 u[4]; uint4 v; };

__device__ __forceinline__ u32 pkbf16(float a, float b) {
  u32 r;
  asm("v_cvt_pk_bf16_f32 %0, %1, %2" : "=v"(r) : "v"(a), "v"(b));
  return r;
}
__device__ __forceinline__ u32 xor32(u32 x) {
  return (u32)__shfl_xor((int)x, 32, 64);
}
__device__ __forceinline__ f32x16 MFMA(short8 a, short8 b, f32x16 c) {
  return __builtin_amdgcn_mfma_f32_32x32x16_bf16(a, b, c, 0, 0, 0);
}
#define Z16 {0.f,0.f,0.f,0.f,0.f,0.f,0.f,0.f,0.f,0.f,0.f,0.f,0.f,0.f,0.f,0.f}

// split 8 f32 into hi/lo bf16 fragments (pair-packed, element e -> k offset e)
__device__ __forceinline__ void pack8(const float* d, F8& hi, F8& lo) {
#pragma unroll
  for (int j = 0; j < 4; ++j) {
    float a = d[2*j], b = d[2*j+1];
    u32 hw = pkbf16(a, b);
    hi.u[j] = hw;
    float ha = __uint_as_float(hw << 16);
    float hb = __uint_as_float(hw & 0xffff0000u);
    lo.u[j] = pkbf16(a - ha, b - hb);
  }
}
__device__ __forceinline__ void packpairs(const float* d, u32* wh, u32* wl) {
  F8 a, b;
  pack8(d, a, b);
#pragma unroll
  for (int j = 0; j < 4; ++j) { wh[j] = a.u[j]; wl[j] = b.u[j]; }
  pack8(d + 8, a, b);
#pragma unroll
  for (int j = 0; j < 4; ++j) { wh[4+j] = a.u[j]; wl[4+j] = b.u[j]; }
}

// D-layout f32[16] (col=lane&31, row=(reg&3)+8*(reg>>2)+4*(lane>>5)) ->
// 4 frags: fr[0]=k0..15 hi, fr[1]=k0..15 lo, fr[2]=k16..31 hi, fr[3]=k16..31 lo.
__device__ __forceinline__ void d2frags(const float* d, int lo_half, F8 fr[4]) {
  u32 wh[8], wl[8];
  packpairs(d, wh, wl);
#pragma unroll
  for (int s = 0; s < 2; ++s) {
    const u32* w = s ? wl : wh;
    u32 c0=xor32(w[0]), c1=xor32(w[1]), c2=xor32(w[2]), c3=xor32(w[3]);
    u32 c4=xor32(w[4]), c5=xor32(w[5]), c6=xor32(w[6]), c7=xor32(w[7]);
    F8& f1 = fr[s];   F8& f2 = fr[2+s];
    f1.u[0] = lo_half ? w[0] : c2;
    f1.u[1] = lo_half ? w[1] : c3;
    f1.u[2] = lo_half ? c0   : w[2];
    f1.u[3] = lo_half ? c1   : w[3];
    f2.u[0] = lo_half ? w[4] : c6;
    f2.u[1] = lo_half ? w[5] : c7;
    f2.u[2] = lo_half ? c4   : w[6];
    f2.u[3] = lo_half ? c5   : w[7];
  }
}

__device__ __forceinline__ void mk_dm(int col, int h, float* dm) {
#pragma unroll
  for (int i = 0; i < 16; ++i) {
    int ro = (i & 3) + 8*(i >> 2) + 4*h;
    dm[i] = (ro == col) ? 1.f : 0.f;
  }
}

// res = p(Y) via Clenshaw; Yf = frags of symmetric Y; all state in D-layout regs.
// FROZEN structure (R2/R7/R8/R10/R11-verified). Do not reorder/split the MFMA chain.
__device__ __forceinline__ void wave_clenshaw(
    const float* __restrict__ coef, int nterms,
    const F8 Yf[4], const float* dm, int lo_half, float* res)
{
  float bc[16], bp[16];
  float cn = coef[nterms-1];
#pragma unroll
  for (int i = 0; i < 16; ++i) { bc[i] = cn*dm[i]; bp[i] = 0.f; }
  for (int kk = nterms-2; kk >= 1; --kk) {
    F8 bf[4];
    d2frags(bc, lo_half, bf);
    f32x16 acc = Z16;
    acc = MFMA(Yf[0].s, bf[0].s, acc);
    acc = MFMA(Yf[0].s, bf[1].s, acc);
    acc = MFMA(Yf[1].s, bf[0].s, acc);
    acc = MFMA(Yf[2].s, bf[2].s, acc);
    acc = MFMA(Yf[2].s, bf[3].s, acc);
    acc = MFMA(Yf[3].s, bf[2].s, acc);
    float ck = coef[kk];
#pragma unroll
    for (int i = 0; i < 16; ++i) {
      float nb = 2.f*acc[i] - bp[i] + ck*dm[i];
      bp[i] = bc[i]; bc[i] = nb;
    }
  }
  F8 bf[4];
  d2frags(bc, lo_half, bf);
  f32x16 acc = Z16;
  acc = MFMA(Yf[0].s, bf[0].s, acc);
  acc = MFMA(Yf[0].s, bf[1].s, acc);
  acc = MFMA(Yf[1].s, bf[0].s, acc);
  acc = MFMA(Yf[2].s, bf[2].s, acc);
  acc = MFMA(Yf[2].s, bf[3].s, acc);
  acc = MFMA(Yf[3].s, bf[2].s, acc);
  float c0h = 0.5f*coef[0];
#pragma unroll
  for (int i = 0; i < 16; ++i) res[i] = acc[i] - bp[i] + c0h*dm[i];
}

// ---------------- kernel 1: S = W X W^T -> log(S), all MFMA, zero LDS ----------
// grid 1536 = 512 tokens x {Q,K,V}; 64 threads (1 wave).
__global__ __launch_bounds__(64, 2) void k_logqkv(
    const float* __restrict__ X, const float* __restrict__ Wq,
    const float* __restrict__ Wk, const float* __restrict__ Wv,
    float* __restrict__ ws)
{
  int gid = blockIdx.x;
  int token = gid / 3, which = gid - token*3;
  const float* W = (which == 0) ? Wq : ((which == 1) ? Wk : Wv);
  int l = threadIdx.x;
  int col = l & 31, h = l >> 5;
  int lo_half = (h == 0);

  // W fragments: Wf[2c]=hi, Wf[2c+1]=lo; slot value W[col][16c+8h+e]
  F8 Wf[8];
#pragma unroll
  for (int c = 0; c < 4; ++c) {
    const float* wp = W + col*64 + 16*c + 8*h;
    float d8[8];
    float4 v0 = *(const float4*)(wp);
    float4 v1 = *(const float4*)(wp + 4);
    d8[0]=v0.x; d8[1]=v0.y; d8[2]=v0.z; d8[3]=v0.w;
    d8[4]=v1.x; d8[5]=v1.y; d8[6]=v1.z; d8[7]=v1.w;
    pack8(d8, Wf[2*c], Wf[2*c+1]);
  }

  // U = X * W^T (64x32) as two 32-row blocks
  f32x16 Ua = Z16, Ub = Z16;
#pragma unroll
  for (int rb = 0; rb < 2; ++rb) {
#pragma unroll
    for (int c = 0; c < 4; ++c) {
      const float* xp = X + (size_t)token*4096 + (size_t)(col + 32*rb)*64 + 16*c + 8*h;
      float d8[8];
      float4 v0 = *(const float4*)(xp);
      float4 v1 = *(const float4*)(xp + 4);
      d8[0]=v0.x; d8[1]=v0.y; d8[2]=v0.z; d8[3]=v0.w;
      d8[4]=v1.x; d8[5]=v1.y; d8[6]=v1.z; d8[7]=v1.w;
      F8 xh, xl;
      pack8(d8, xh, xl);
      f32x16& U = rb ? Ub : Ua;
      U = MFMA(xh.s, Wf[2*c].s,   U);
      U = MFMA(xh.s, Wf[2*c+1].s, U);
      U = MFMA(xl.s, Wf[2*c].s,   U);
    }
  }

  // U (D-layout) -> B-frags for S-step: chunks 0..3 of K=64
  float ua[16], ub[16];
#pragma unroll
  for (int i = 0; i < 16; ++i) { ua[i] = Ua[i]; ub[i] = Ub[i]; }
  F8 Uf[8], t4[4];
  d2frags(ua, lo_half, t4);
  Uf[0]=t4[0]; Uf[1]=t4[1]; Uf[2]=t4[2]; Uf[3]=t4[3];
  d2frags(ub, lo_half, t4);
  Uf[4]=t4[0]; Uf[5]=t4[1]; Uf[6]=t4[2]; Uf[7]=t4[3];

  // S = W * U (32x32)
  f32x16 S = Z16;
#pragma unroll
  for (int c = 0; c < 4; ++c) {
    S = MFMA(Wf[2*c].s,   Uf[2*c].s,   S);
    S = MFMA(Wf[2*c].s,   Uf[2*c+1].s, S);
    S = MFMA(Wf[2*c+1].s, Uf[2*c].s,   S);
  }

  // affine map to Chebyshev domain, then log via Clenshaw
  float dm[16], y[16], res[16];
  mk_dm(col, h, dm);
  const float scl = (float)(2.0/(LOG_B-LOG_A));
  const float shf = (float)((LOG_A+LOG_B)/(LOG_B-LOG_A));
#pragma unroll
  for (int i = 0; i < 16; ++i) y[i] = scl*S[i] - shf*dm[i];
  F8 Yf[4];
  d2frags(y, lo_half, Yf);
  wave_clenshaw(LOGC, NLOG, Yf, dm, lo_half, res);

  if (which == 2) {
    float* LV = ws + WS_LV + (size_t)token*1024 + l*16;
#pragma unroll
    for (int g = 0; g < 4; ++g)
      *(float4*)(LV + 4*g) = make_float4(res[4*g], res[4*g+1], res[4*g+2], res[4*g+3]);
  } else {
    u32 wh[8], wl[8];
    packpairs(res, wh, wl);
    u32* hp = (u32*)ws + (which ? WS_KHI : WS_QHI) + (size_t)token*512 + l*8;
    u32* lp = (u32*)ws + (which ? WS_KLO : WS_QLO) + (size_t)token*512 + l*8;
    *(uint4*)(hp)     = make_uint4(wh[0], wh[1], wh[2], wh[3]);
    *(uint4*)(hp + 4) = make_uint4(wh[4], wh[5], wh[6], wh[7]);
    *(uint4*)(lp)     = make_uint4(wl[0], wl[1], wl[2], wl[3]);
    *(uint4*)(lp + 4) = make_uint4(wl[4], wl[5], wl[6], wl[7]);
    float nrm = 0.f;
#pragma unroll
    for (int i = 0; i < 16; ++i) nrm += res[i]*res[i];
#pragma unroll
    for (int off = 32; off >= 1; off >>= 1) nrm += __shfl_xor(nrm, off, 64);
    if (l == 0) ws[WS_NORM + which*512 + token] = nrm;
  }
}

// ---------------- kernel 2: Gram via MFMA + energies + softmax -> weights ------
// grid 16 = 8 b x 2 jt(32 j each); 256 threads = 4 waves (rb = w&1, kh = w>>1).
__global__ __launch_bounds__(256) void k_energy(float* __restrict__ ws)
{
  __shared__ float sG[2][32][68];
  __shared__ float sS[32][68];
  __shared__ float sMax[32], sInv[32];
  const u32* Qhi = (const u32*)ws + WS_QHI;
  const u32* Qlo = (const u32*)ws + WS_QLO;
  const u32* Khi = (const u32*)ws + WS_KHI;
  const u32* Klo = (const u32*)ws + WS_KLO;
  const float* norms = ws + WS_NORM;
  float* wgt = ws + WS_WGT;

  int b = blockIdx.x >> 1, j0 = (blockIdx.x & 1)*32;
  int t = threadIdx.x;
  int w = t >> 6, l = t & 63;
  int rb = w & 1, kh = w >> 1;
  int col = l & 31, h = l >> 5;
  int itok = b*64 + rb*32 + col;   // A rows: K-logs
  int jtok = b*64 + j0 + col;      // B cols: Q-logs

  const u32* Ah = Khi + (size_t)itok*512;
  const u32* Al = Klo + (size_t)itok*512;
  const u32* Bh = Qhi + (size_t)jtok*512;
  const u32* Bl = Qlo + (size_t)jtok*512;

  f32x16 acc = Z16;
  for (int c = kh*32; c < kh*32 + 32; ++c) {
    int off = 8*c + 4*h;
    F8 ah, al, bh, bl;
    ah.v = *(const uint4*)(Ah + off);
    al.v = *(const uint4*)(Al + off);
    bh.v = *(const uint4*)(Bh + off);
    bl.v = *(const uint4*)(Bl + off);
    acc = MFMA(ah.s, bh.s, acc);
    acc = MFMA(ah.s, bl.s, acc);
    acc = MFMA(al.s, bh.s, acc);
  }
#pragma unroll
  for (int g = 0; g < 4; ++g) {
    int ro = rb*32 + 8*g + 4*h;
    *(float4*)(&sG[kh][col][ro]) = make_float4(acc[4*g], acc[4*g+1], acc[4*g+2], acc[4*g+3]);
  }
  __syncthreads();

  int j = t & 31, ig = t >> 5;
  float nq = norms[b*64 + j0 + j];
#pragma unroll
  for (int i = ig*8; i < ig*8 + 8; ++i) {
    float g = sG[0][j][i] + sG[1][j][i];
    float e = fmaxf(norms[512 + b*64 + i] + nq - 2.f*g, 0.f);
    sS[j][i] = 1.f/(1.f + log1pf(e));
  }
  __syncthreads();
  if (t < 32) {
    float m = -1e30f;
    for (int i = 0; i < 64; ++i) m = fmaxf(m, sS[t][i]);
    float s = 0.f;
    for (int i = 0; i < 64; ++i) s += expf(sS[t][i] - m);
    sMax[t] = m; sInv[t] = 1.f/s;
  }
  __syncthreads();
  float m = sMax[j], inv = sInv[j];
#pragma unroll
  for (int i = ig*8; i < ig*8 + 8; ++i)
    wgt[(size_t)(b*64 + j0 + j)*64 + i] = expf(sS[j][i] - m)*inv;
}

// ---------------- kernel 3: weighted log-mean + matrix exp (MFMA Clenshaw) -----
// grid 128; 256 threads = 4 waves, wave = one (b,j).
__global__ __launch_bounds__(256, 2) void k_meanexp(
    const float* __restrict__ ws_c, float* __restrict__ out)
{
  __shared__ float sW[4][64];
  const float* LV  = ws_c + WS_LV;
  const float* wgt = ws_c + WS_WGT;

  int wv = threadIdx.x >> 6, l = threadIdx.x & 63;
  int bj = blockIdx.x*4 + wv;
  int b = bj >> 6;
  int col = l & 31, h = l >> 5;
  int lo_half = (h == 0);

  sW[wv][l] = wgt[(size_t)bj*64 + l];   // intra-wave LDS: in-order, no barrier

  float acc[16];
#pragma unroll
  for (int i = 0; i < 16; ++i) acc[i] = 0.f;
  const float* vb = LV + (size_t)b*65536 + l*16;
#pragma unroll 4
  for (int i = 0; i < 64; ++i) {
    float wi = sW[wv][i];
    const float* vp = vb + (size_t)i*1024;
    float4 a0 = *(const float4*)(vp);
    float4 a1 = *(const float4*)(vp + 4);
    float4 a2 = *(const float4*)(vp + 8);
    float4 a3 = *(const float4*)(vp + 12);
    acc[0]  = fmaf(wi, a0.x, acc[0]);  acc[1]  = fmaf(wi, a0.y, acc[1]);
    acc[2]  = fmaf(wi, a0.z, acc[2]);  acc[3]  = fmaf(wi, a0.w, acc[3]);
    acc[4]  = fmaf(wi, a1.x, acc[4]);  acc[5]  = fmaf(wi, a1.y, acc[5]);
    acc[6]  = fmaf(wi, a1.z, acc[6]);  acc[7]  = fmaf(wi, a1.w, acc[7]);
    acc[8]  = fmaf(wi, a2.x, acc[8]);  acc[9]  = fmaf(wi, a2.y, acc[9]);
    acc[10] = fmaf(wi, a2.z, acc[10]); acc[11] = fmaf(wi, a2.w, acc[11]);
    acc[12] = fmaf(wi, a3.x, acc[12]); acc[13] = fmaf(wi, a3.y, acc[13]);
    acc[14] = fmaf(wi, a3.z, acc[14]); acc[15] = fmaf(wi, a3.w, acc[15]);
  }

  float dm[16], y[16], res[16];
  mk_dm(col, h, dm);
  const float scl = (float)(2.0/(EXP_B-EXP_A));
  const float shf = (float)((EXP_A+EXP_B)/(EXP_B-EXP_A));
#pragma unroll
  for (int i = 0; i < 16; ++i) y[i] = scl*acc[i] - shf*dm[i];
  F8 Yf[4];
  d2frags(y, lo_half, Yf);
  wave_clenshaw(EXPC, NEXP, Yf, dm, lo_half, res);

  float* og = out + (size_t)bj*1024;
#pragma unroll
  for (int i = 0; i < 16; ++i) {
    int ro = (i & 3) + 8*(i >> 2) + 4*h;
    og[ro*32 + col] = res[i];
  }
}

extern "C" void kernel_launch(void* const* d_in, const int* in_sizes, int n_in,
                              void* d_out, int out_size, void* d_ws, size_t ws_size,
                              hipStream_t stream) {
  const float* X  = (const float*)d_in[0];
  const float* Wq = (const float*)d_in[1];
  const float* Wk = (const float*)d_in[2];
  const float* Wv = (const float*)d_in[3];
  float* out = (float*)d_out;
  float* ws  = (float*)d_ws;

  hipLaunchKernelGGL(k_logqkv,  dim3(1536), dim3(64),  0, stream, X, Wq, Wk, Wv, ws);
  hipLaunchKernelGGL(k_energy,  dim3(16),   dim3(256), 0, stream, ws);
  hipLaunchKernelGGL(k_meanexp, dim3(128),  dim3(256), 0, stream, ws, out);
}